// Round 1
// baseline (1014.878 us; speedup 1.0000x reference)
//
#include <hip/hip_runtime.h>
#include <math.h>

#define BB 8
#define CCH 256
#define QQ 4
#define NN 1600          // H*W
#define BQN 32           // B*Q
#define EPSF 1e-5f

// ---------------- fake-quant weights + gamma ----------------
// blocks 0..1023: one block per (matrix, row). block 1024: gamma (axis=None).
__global__ void quant_weights_kernel(const float* Wq, const float* Wk,
                                     const float* Wv, const float* Wp,
                                     const float* gamma,
                                     float* wq, float* wk, float* wv, float* wp,
                                     float* gq) {
  __shared__ float red[256];
  int blk = blockIdx.x;
  int tid = threadIdx.x;
  if (blk < 1024) {
    int mat = blk >> 8;
    int row = blk & 255;
    const float* W = (mat == 0) ? Wq : (mat == 1) ? Wk : (mat == 2) ? Wv : Wp;
    float* O       = (mat == 0) ? wq : (mat == 1) ? wk : (mat == 2) ? wv : wp;
    float w = W[row * 256 + tid];
    red[tid] = fabsf(w);
    __syncthreads();
    for (int s = 128; s > 0; s >>= 1) {
      if (tid < s) red[tid] = fmaxf(red[tid], red[tid + s]);
      __syncthreads();
    }
    float s = red[0] / 127.0f + 1e-8f;
    float q = fminf(fmaxf(rintf(w / s), -127.0f), 127.0f) * s;
    O[row * 256 + tid] = q;
  } else {
    float g = gamma[tid];
    red[tid] = fabsf(g);
    __syncthreads();
    for (int s = 128; s > 0; s >>= 1) {
      if (tid < s) red[tid] = fmaxf(red[tid], red[tid + s]);
      __syncthreads();
    }
    float s = red[0] / 127.0f + 1e-8f;
    float q = fminf(fmaxf(rintf(g / s), -127.0f), 127.0f) * s;
    gq[tid] = q;
  }
}

// ---------------- QKV projection ----------------
// Y[(b*Q+q)][o][n] = sum_c W[o][c] * x[b][c][q][n] + bias[o]
// grid: (NN/64, CCH/64, 3*BQN), block 256
__global__ void proj_qkv_kernel(const float* __restrict__ x,
                                const float* __restrict__ wq,
                                const float* __restrict__ wk,
                                const float* __restrict__ wv,
                                const float* __restrict__ bq,
                                const float* __restrict__ bk,
                                const float* __restrict__ bv,
                                float* __restrict__ qb,
                                float* __restrict__ kb,
                                float* __restrict__ vb) {
  int nT = blockIdx.x * 64;
  int oT = blockIdx.y * 64;
  int z = blockIdx.z;
  int proj = z >> 5;
  int bqi = z & 31;
  int b = bqi >> 2, q = bqi & 3;
  const float* W; const float* bias; float* Y;
  if (proj == 0)      { W = wq; bias = bq; Y = qb; }
  else if (proj == 1) { W = wk; bias = bk; Y = kb; }
  else                { W = wv; bias = bv; Y = vb; }
  const float* X = x + (size_t)(b * CCH * QQ + q) * NN;  // [c][n], row stride QQ*NN
  float* Yb = Y + (size_t)bqi * CCH * NN;                // [o][n], row stride NN

  __shared__ float At[64][17];
  __shared__ float Bt[16][64];
  int tid = threadIdx.x;
  int tx = tid & 15, ty = tid >> 4;
  float acc[4][4] = {};
  for (int kt = 0; kt < 256; kt += 16) {
#pragma unroll
    for (int i = 0; i < 4; i++) {
      int idx = tid + i * 256;
      int r = idx >> 4, c = idx & 15;
      At[r][c] = W[(oT + r) * 256 + kt + c];
    }
#pragma unroll
    for (int i = 0; i < 4; i++) {
      int idx = tid + i * 256;
      int r = idx >> 6, c = idx & 63;
      Bt[r][c] = X[(size_t)(kt + r) * (QQ * NN) + nT + c];
    }
    __syncthreads();
#pragma unroll
    for (int k = 0; k < 16; k++) {
      float a[4], bv_[4];
#pragma unroll
      for (int i = 0; i < 4; i++) a[i] = At[ty * 4 + i][k];
#pragma unroll
      for (int j = 0; j < 4; j++) bv_[j] = Bt[k][tx * 4 + j];
#pragma unroll
      for (int i = 0; i < 4; i++)
#pragma unroll
        for (int j = 0; j < 4; j++)
          acc[i][j] = fmaf(a[i], bv_[j], acc[i][j]);
    }
    __syncthreads();
  }
#pragma unroll
  for (int i = 0; i < 4; i++) {
    int o = oT + ty * 4 + i;
    float bi = bias[o];
#pragma unroll
    for (int j = 0; j < 4; j++)
      Yb[(size_t)o * NN + nT + tx * 4 + j] = acc[i][j] + bi;
  }
}

// ---------------- scores: S[c][d] = 0.125 * sum_n Q[c][n]*K[d][n] ----------------
// grid: (CCH/64, CCH/64, BQN)
__global__ void scores_kernel(const float* __restrict__ qbuf,
                              const float* __restrict__ kbuf,
                              float* __restrict__ sb) {
  int dT = blockIdx.x * 64;
  int cT = blockIdx.y * 64;
  int bqi = blockIdx.z;
  const float* Qh = qbuf + (size_t)bqi * CCH * NN;
  const float* Kh = kbuf + (size_t)bqi * CCH * NN;
  float* S = sb + (size_t)bqi * CCH * CCH;
  __shared__ float At[64][17];
  __shared__ float Bt[64][17];
  int tid = threadIdx.x;
  int tx = tid & 15, ty = tid >> 4;
  float acc[4][4] = {};
  for (int kt = 0; kt < NN; kt += 16) {
#pragma unroll
    for (int i = 0; i < 4; i++) {
      int idx = tid + i * 256;
      int r = idx >> 4, c = idx & 15;
      At[r][c] = Qh[(size_t)(cT + r) * NN + kt + c];
      Bt[r][c] = Kh[(size_t)(dT + r) * NN + kt + c];
    }
    __syncthreads();
#pragma unroll
    for (int k = 0; k < 16; k++) {
      float a[4], bv_[4];
#pragma unroll
      for (int i = 0; i < 4; i++) a[i] = At[ty * 4 + i][k];
#pragma unroll
      for (int j = 0; j < 4; j++) bv_[j] = Bt[tx * 4 + j][k];
#pragma unroll
      for (int i = 0; i < 4; i++)
#pragma unroll
        for (int j = 0; j < 4; j++)
          acc[i][j] = fmaf(a[i], bv_[j], acc[i][j]);
    }
    __syncthreads();
  }
#pragma unroll
  for (int i = 0; i < 4; i++)
#pragma unroll
    for (int j = 0; j < 4; j++)
      S[(size_t)(cT + ty * 4 + i) * CCH + dT + tx * 4 + j] = acc[i][j] * 0.125f;
}

// ---------------- softmax over last dim (rows of 256) ----------------
__global__ void softmax_kernel(float* __restrict__ sb) {
  size_t row = blockIdx.x;
  float* r = sb + row * CCH;
  int tid = threadIdx.x;
  __shared__ float red[256];
  float v = r[tid];
  red[tid] = v;
  __syncthreads();
  for (int s = 128; s > 0; s >>= 1) {
    if (tid < s) red[tid] = fmaxf(red[tid], red[tid + s]);
    __syncthreads();
  }
  float m = red[0];
  __syncthreads();
  float e = expf(v - m);
  red[tid] = e;
  __syncthreads();
  for (int s = 128; s > 0; s >>= 1) {
    if (tid < s) red[tid] += red[tid + s];
    __syncthreads();
  }
  r[tid] = e / red[0];
}

// ---------------- O[c][n] = sum_d S[c][d] * V[d][n] ----------------
// grid: (NN/64, CCH/64, BQN). Writes into qbuf (q no longer needed).
__global__ void attnv_kernel(const float* __restrict__ sb,
                             const float* __restrict__ vbuf,
                             float* __restrict__ ob) {
  int nT = blockIdx.x * 64;
  int cT = blockIdx.y * 64;
  int bqi = blockIdx.z;
  const float* S = sb + (size_t)bqi * CCH * CCH;
  const float* V = vbuf + (size_t)bqi * CCH * NN;
  float* O = ob + (size_t)bqi * CCH * NN;
  __shared__ float At[64][17];
  __shared__ float Bt[16][64];
  int tid = threadIdx.x;
  int tx = tid & 15, ty = tid >> 4;
  float acc[4][4] = {};
  for (int kt = 0; kt < CCH; kt += 16) {
#pragma unroll
    for (int i = 0; i < 4; i++) {
      int idx = tid + i * 256;
      int r = idx >> 4, c = idx & 15;
      At[r][c] = S[(size_t)(cT + r) * CCH + kt + c];
    }
#pragma unroll
    for (int i = 0; i < 4; i++) {
      int idx = tid + i * 256;
      int r = idx >> 6, c = idx & 63;
      Bt[r][c] = V[(size_t)(kt + r) * NN + nT + c];
    }
    __syncthreads();
#pragma unroll
    for (int k = 0; k < 16; k++) {
      float a[4], bv_[4];
#pragma unroll
      for (int i = 0; i < 4; i++) a[i] = At[ty * 4 + i][k];
#pragma unroll
      for (int j = 0; j < 4; j++) bv_[j] = Bt[k][tx * 4 + j];
#pragma unroll
      for (int i = 0; i < 4; i++)
#pragma unroll
        for (int j = 0; j < 4; j++)
          acc[i][j] = fmaf(a[i], bv_[j], acc[i][j]);
    }
    __syncthreads();
  }
#pragma unroll
  for (int i = 0; i < 4; i++)
#pragma unroll
    for (int j = 0; j < 4; j++)
      O[(size_t)(cT + ty * 4 + i) * NN + nT + tx * 4 + j] = acc[i][j];
}

// ---------------- output projection ----------------
// out[b][o][q][n] = sum_c Wp[o][c] * O[(b*Q+q)][c][n] + bp[o]
// grid: (NN/64, CCH/64, BQN)
__global__ void proj_out_kernel(const float* __restrict__ ob,
                                const float* __restrict__ wp,
                                const float* __restrict__ bp,
                                float* __restrict__ out) {
  int nT = blockIdx.x * 64;
  int oT = blockIdx.y * 64;
  int bqi = blockIdx.z;
  int b = bqi >> 2, q = bqi & 3;
  const float* X = ob + (size_t)bqi * CCH * NN;          // [c][n], stride NN
  float* Yb = out + (size_t)(b * CCH * QQ + q) * NN;     // [o][n], stride QQ*NN
  __shared__ float At[64][17];
  __shared__ float Bt[16][64];
  int tid = threadIdx.x;
  int tx = tid & 15, ty = tid >> 4;
  float acc[4][4] = {};
  for (int kt = 0; kt < 256; kt += 16) {
#pragma unroll
    for (int i = 0; i < 4; i++) {
      int idx = tid + i * 256;
      int r = idx >> 4, c = idx & 15;
      At[r][c] = wp[(oT + r) * 256 + kt + c];
    }
#pragma unroll
    for (int i = 0; i < 4; i++) {
      int idx = tid + i * 256;
      int r = idx >> 6, c = idx & 63;
      Bt[r][c] = X[(size_t)(kt + r) * NN + nT + c];
    }
    __syncthreads();
#pragma unroll
    for (int k = 0; k < 16; k++) {
      float a[4], bv_[4];
#pragma unroll
      for (int i = 0; i < 4; i++) a[i] = At[ty * 4 + i][k];
#pragma unroll
      for (int j = 0; j < 4; j++) bv_[j] = Bt[k][tx * 4 + j];
#pragma unroll
      for (int i = 0; i < 4; i++)
#pragma unroll
        for (int j = 0; j < 4; j++)
          acc[i][j] = fmaf(a[i], bv_[j], acc[i][j]);
    }
    __syncthreads();
  }
#pragma unroll
  for (int i = 0; i < 4; i++) {
    int o = oT + ty * 4 + i;
    float bi = bp[o];
#pragma unroll
    for (int j = 0; j < 4; j++)
      Yb[(size_t)o * (QQ * NN) + nT + tx * 4 + j] = acc[i][j] + bi;
  }
}

// ---------------- per-channel mean/var over (b,q,n) ----------------
__global__ void stats_kernel(const float* __restrict__ out, float* __restrict__ stats) {
  int o = blockIdx.x;
  int tid = threadIdx.x;
  __shared__ float rs[256], rs2[256];
  float s = 0.f, s2 = 0.f;
  for (int i = tid; i < BQN * NN; i += 256) {
    int bq = i / NN, n = i - bq * NN;
    int b = bq >> 2, q = bq & 3;
    float v = out[(size_t)((b * CCH + o) * QQ + q) * NN + n];
    s += v; s2 += v * v;
  }
  rs[tid] = s; rs2[tid] = s2;
  __syncthreads();
  for (int st = 128; st > 0; st >>= 1) {
    if (tid < st) { rs[tid] += rs[tid + st]; rs2[tid] += rs2[tid + st]; }
    __syncthreads();
  }
  if (tid == 0) {
    float mean = rs[0] / (float)(BQN * NN);
    float var = rs2[0] / (float)(BQN * NN) - mean * mean;
    stats[o] = mean;
    stats[CCH + o] = var;
  }
}

// ---------------- batch-norm apply ----------------
__global__ void bn_kernel(float* __restrict__ out, const float* __restrict__ stats,
                          const float* __restrict__ gq, const float* __restrict__ beta) {
  size_t idx = (size_t)blockIdx.x * 256 + threadIdx.x;
  if (idx >= (size_t)BB * CCH * QQ * NN) return;
  int o = (int)((idx / (QQ * NN)) % CCH);
  float mean = stats[o], var = stats[CCH + o];
  out[idx] = (out[idx] - mean) * rsqrtf(var + EPSF) * gq[o] + beta[o];
}

extern "C" void kernel_launch(void* const* d_in, const int* in_sizes, int n_in,
                              void* d_out, int out_size, void* d_ws, size_t ws_size,
                              hipStream_t stream) {
  const float* x     = (const float*)d_in[0];
  const float* Wq    = (const float*)d_in[1];
  const float* bq    = (const float*)d_in[2];
  const float* Wk    = (const float*)d_in[3];
  const float* bk    = (const float*)d_in[4];
  const float* Wv    = (const float*)d_in[5];
  const float* bv    = (const float*)d_in[6];
  const float* Wp    = (const float*)d_in[7];
  const float* bp    = (const float*)d_in[8];
  const float* gamma = (const float*)d_in[9];
  const float* beta  = (const float*)d_in[10];
  float* out = (float*)d_out;

  float* wsf  = (float*)d_ws;
  float* wq   = wsf;                 // 65536
  float* wk   = wq + 65536;
  float* wv   = wk + 65536;
  float* wp   = wv + 65536;
  float* gq   = wp + 65536;          // 256
  float* st   = gq + 256;            // 512
  float* qb   = st + 512;            // 13107200 each
  float* kb   = qb + (size_t)BQN * CCH * NN;
  float* vb   = kb + (size_t)BQN * CCH * NN;
  float* sb   = vb + (size_t)BQN * CCH * NN;  // 32*256*256

  quant_weights_kernel<<<1025, 256, 0, stream>>>(Wq, Wk, Wv, Wp, gamma,
                                                 wq, wk, wv, wp, gq);
  proj_qkv_kernel<<<dim3(NN / 64, CCH / 64, 3 * BQN), 256, 0, stream>>>(
      x, wq, wk, wv, bq, bk, bv, qb, kb, vb);
  scores_kernel<<<dim3(CCH / 64, CCH / 64, BQN), 256, 0, stream>>>(qb, kb, sb);
  softmax_kernel<<<BQN * CCH, 256, 0, stream>>>(sb);
  attnv_kernel<<<dim3(NN / 64, CCH / 64, BQN), 256, 0, stream>>>(sb, vb, qb);
  proj_out_kernel<<<dim3(NN / 64, CCH / 64, BQN), 256, 0, stream>>>(qb, wp, bp, out);
  stats_kernel<<<CCH, 256, 0, stream>>>(out, st);
  bn_kernel<<<(BB * CCH * QQ * NN + 255) / 256, 256, 0, stream>>>(out, st, gq, beta);
}

// Round 2
// 371.170 us; speedup vs baseline: 2.7343x; 2.7343x over previous
//
#include <hip/hip_runtime.h>
#include <math.h>

#define BB 8
#define CCH 256
#define QQ 4
#define NN 1600          // H*W
#define BQN 32           // B*Q
#define SP 51200         // BQN*NN total spatial
#define EPSF 1e-5f

typedef __attribute__((ext_vector_type(8))) short bf16x8;  // 8 bf16 (4 VGPRs)
typedef __attribute__((ext_vector_type(4))) float f32x4;

static __device__ inline ushort f2bf(float f) {
  union { float f; unsigned u; } v; v.f = f;
  return (ushort)((v.u + 0x7fffu + ((v.u >> 16) & 1u)) >> 16);  // RNE
}

// ---------------- fake-quant weights (-> bf16) + gamma (-> fp32) ----------------
__global__ void quant_weights_kernel(const float* Wq, const float* Wk,
                                     const float* Wv, const float* Wp,
                                     const float* gamma,
                                     ushort* wq, ushort* wk, ushort* wv, ushort* wp,
                                     float* gq) {
  __shared__ float red[256];
  int blk = blockIdx.x;
  int tid = threadIdx.x;
  if (blk < 1024) {
    int mat = blk >> 8;
    int row = blk & 255;
    const float* W = (mat == 0) ? Wq : (mat == 1) ? Wk : (mat == 2) ? Wv : Wp;
    ushort* O      = (mat == 0) ? wq : (mat == 1) ? wk : (mat == 2) ? wv : wp;
    float w = W[row * 256 + tid];
    red[tid] = fabsf(w);
    __syncthreads();
    for (int s = 128; s > 0; s >>= 1) {
      if (tid < s) red[tid] = fmaxf(red[tid], red[tid + s]);
      __syncthreads();
    }
    float s = red[0] / 127.0f + 1e-8f;
    float q = fminf(fmaxf(rintf(w / s), -127.0f), 127.0f) * s;
    O[row * 256 + tid] = f2bf(q);
  } else {
    float g = gamma[tid];
    red[tid] = fabsf(g);
    __syncthreads();
    for (int s = 128; s > 0; s >>= 1) {
      if (tid < s) red[tid] = fmaxf(red[tid], red[tid + s]);
      __syncthreads();
    }
    float s = red[0] / 127.0f + 1e-8f;
    float q = fminf(fmaxf(rintf(g / s), -127.0f), 127.0f) * s;
    gq[tid] = q;
  }
}

// ---------------- transpose x: [b][c][q][n] fp32 -> xT[s=bqi*NN+n][c] bf16 ----------------
// grid (NN/64, CCH/64, BQN), block 256
__global__ __launch_bounds__(256)
void transpose_x_kernel(const float* __restrict__ x, ushort* __restrict__ xT) {
  int bqi = blockIdx.z, b = bqi >> 2, q = bqi & 3;
  int s0 = blockIdx.x * 64, c0 = blockIdx.y * 64;
  __shared__ ushort lT[64 * 66];
  int tid = threadIdx.x;
  int c = tid >> 2, nch = (tid & 3) * 16;
  const float* xp = x + ((size_t)(b * CCH + c0 + c) * QQ + q) * NN + s0 + nch;
#pragma unroll
  for (int j = 0; j < 4; j++) {
    float4 f = ((const float4*)xp)[j];
    lT[c * 66 + nch + j * 4 + 0] = f2bf(f.x);
    lT[c * 66 + nch + j * 4 + 1] = f2bf(f.y);
    lT[c * 66 + nch + j * 4 + 2] = f2bf(f.z);
    lT[c * 66 + nch + j * 4 + 3] = f2bf(f.w);
  }
  __syncthreads();
  int n = tid >> 2, cch = (tid & 3) * 16;
  union { ushort u[16]; int4 v[2]; } o;
#pragma unroll
  for (int i = 0; i < 16; i++) o.u[i] = lT[(cch + i) * 66 + n];
  ushort* dst = xT + (size_t)(bqi * NN + s0 + n) * CCH + c0 + cch;
  *(int4*)dst = o.v[0];
  *((int4*)dst + 1) = o.v[1];
}

// ---------------- generic bf16 MFMA GEMM: C[M][N] = A[M][K] * B[N][K]^T ----------------
// Both A and B row-major with contiguous K (contraction). 64x64 block tile,
// 4 waves, each wave = 16 rows x 64 cols via 4x mfma_f32_16x16x32_bf16.
// Epilogue variants:
//  0: bf16 out [m][n] + bias[m]        1: bf16 out [n][m] + bias[m] (transposed)
//  2: f32 out [m][n] * scale           3: bf16 out [n][m] (transposed, no bias)
//  4: f32 out strided into [b][o][q][n] + bias[m]
template<int EPI>
__global__ __launch_bounds__(256)
void gemm_bt(const ushort* __restrict__ A, int lda, long sA,
             const ushort* __restrict__ B, int ldb, long sB,
             void* __restrict__ Cv, int ldc, long sC,
             const float* __restrict__ bias, float scale, int K)
{
  __shared__ ushort lA[64 * 40];   // 64 rows x 32 k (padded to 40)
  __shared__ ushort lB[64 * 40];
  __shared__ float lC[64 * 65];
  int z = blockIdx.z;
  int mBase = blockIdx.y * 64;
  int nBase = blockIdx.x * 64;
  const ushort* Ab = A + z * sA + (size_t)mBase * lda;
  const ushort* Bb = B + z * sB + (size_t)nBase * ldb;
  int tid = threadIdx.x;
  int wave = tid >> 6, lane = tid & 63;
  int lrow = tid >> 2, lcol = (tid & 3) * 8;      // staging coords
  int col = lane & 15, quad = lane >> 4;          // MFMA coords
  f32x4 acc0 = {0.f, 0.f, 0.f, 0.f};
  f32x4 acc1 = acc0, acc2 = acc0, acc3 = acc0;
  const ushort* ga = Ab + (size_t)lrow * lda + lcol;
  const ushort* gb = Bb + (size_t)lrow * ldb + lcol;

  for (int kt = 0; kt < K; kt += 32) {
    int4 av = *(const int4*)(ga + kt);
    int4 bv = *(const int4*)(gb + kt);
    __syncthreads();
    *(int4*)(&lA[lrow * 40 + lcol]) = av;
    *(int4*)(&lB[lrow * 40 + lcol]) = bv;
    __syncthreads();
    bf16x8 af = *(const bf16x8*)(&lA[(wave * 16 + col) * 40 + quad * 8]);
    bf16x8 b0 = *(const bf16x8*)(&lB[(0 * 16 + col) * 40 + quad * 8]);
    bf16x8 b1 = *(const bf16x8*)(&lB[(1 * 16 + col) * 40 + quad * 8]);
    bf16x8 b2 = *(const bf16x8*)(&lB[(2 * 16 + col) * 40 + quad * 8]);
    bf16x8 b3 = *(const bf16x8*)(&lB[(3 * 16 + col) * 40 + quad * 8]);
    acc0 = __builtin_amdgcn_mfma_f32_16x16x32_bf16(af, b0, acc0, 0, 0, 0);
    acc1 = __builtin_amdgcn_mfma_f32_16x16x32_bf16(af, b1, acc1, 0, 0, 0);
    acc2 = __builtin_amdgcn_mfma_f32_16x16x32_bf16(af, b2, acc2, 0, 0, 0);
    acc3 = __builtin_amdgcn_mfma_f32_16x16x32_bf16(af, b3, acc3, 0, 0, 0);
  }
  __syncthreads();
  // C/D layout: col = lane&15, row(in 16x16 tile) = quad*4 + reg  [m89/m91]
  {
    int rbase = wave * 16 + quad * 4;
#pragma unroll
    for (int r = 0; r < 4; r++) {
      lC[(rbase + r) * 65 +  0 + col] = acc0[r];
      lC[(rbase + r) * 65 + 16 + col] = acc1[r];
      lC[(rbase + r) * 65 + 32 + col] = acc2[r];
      lC[(rbase + r) * 65 + 48 + col] = acc3[r];
    }
  }
  __syncthreads();
  int orow = tid >> 2;            // 0..63
  int ochk = (tid & 3) * 16;      // chunk of 16 along the other dim

  if (EPI == 0) {
    float bi = bias[mBase + orow];
    union { ushort u[16]; int4 v[2]; } o;
#pragma unroll
    for (int i = 0; i < 16; i++) o.u[i] = f2bf(lC[orow * 65 + ochk + i] + bi);
    ushort* C = (ushort*)Cv + (size_t)z * sC + (size_t)(mBase + orow) * ldc + nBase + ochk;
    *(int4*)C = o.v[0];
    *((int4*)C + 1) = o.v[1];
  } else if (EPI == 1) {
    union { ushort u[16]; int4 v[2]; } o;
#pragma unroll
    for (int i = 0; i < 16; i++)
      o.u[i] = f2bf(lC[(ochk + i) * 65 + orow] + bias[mBase + ochk + i]);
    ushort* C = (ushort*)Cv + (size_t)z * sC + (size_t)(nBase + orow) * ldc + mBase + ochk;
    *(int4*)C = o.v[0];
    *((int4*)C + 1) = o.v[1];
  } else if (EPI == 2) {
    float* C = (float*)Cv + (size_t)z * sC + (size_t)(mBase + orow) * ldc + nBase + ochk;
#pragma unroll
    for (int i = 0; i < 16; i++) C[i] = lC[orow * 65 + ochk + i] * scale;
  } else if (EPI == 3) {
    union { ushort u[16]; int4 v[2]; } o;
#pragma unroll
    for (int i = 0; i < 16; i++) o.u[i] = f2bf(lC[(ochk + i) * 65 + orow]);
    ushort* C = (ushort*)Cv + (size_t)z * sC + (size_t)(nBase + orow) * ldc + mBase + ochk;
    *(int4*)C = o.v[0];
    *((int4*)C + 1) = o.v[1];
  } else {  // EPI 4: fp32 out into out[b][o][q][n], bias[m]
    int s0 = nBase;
    int bqi = s0 / 1600;
    int n0 = s0 - bqi * 1600;
    int b = bqi >> 2, q = bqi & 3;
    float bi = bias[mBase + orow];
    float* C = (float*)Cv + (size_t)b * (CCH * QQ * NN)
             + (size_t)(mBase + orow) * (QQ * NN) + (size_t)q * NN + n0 + ochk;
#pragma unroll
    for (int i = 0; i < 16; i++) C[i] = lC[orow * 65 + ochk + i] + bi;
  }
}

// ---------------- softmax over rows of 256: fp32 S -> bf16 P ----------------
__global__ void softmax_kernel(const float* __restrict__ S, ushort* __restrict__ P) {
  size_t row = blockIdx.x;
  const float* r = S + row * CCH;
  int tid = threadIdx.x;
  __shared__ float red[256];
  float v = r[tid];
  red[tid] = v;
  __syncthreads();
  for (int s = 128; s > 0; s >>= 1) {
    if (tid < s) red[tid] = fmaxf(red[tid], red[tid + s]);
    __syncthreads();
  }
  float m = red[0];
  __syncthreads();
  float e = expf(v - m);
  red[tid] = e;
  __syncthreads();
  for (int s = 128; s > 0; s >>= 1) {
    if (tid < s) red[tid] += red[tid + s];
    __syncthreads();
  }
  P[row * CCH + tid] = f2bf(e / red[0]);
}

// ---------------- per-channel mean/var over (b,q,n) ----------------
__global__ void stats_kernel(const float* __restrict__ out, float* __restrict__ stats) {
  int o = blockIdx.x;
  int tid = threadIdx.x;
  __shared__ float rs[256], rs2[256];
  float s = 0.f, s2 = 0.f;
  for (int i = tid; i < BQN * NN; i += 256) {
    int bq = i / NN, n = i - bq * NN;
    int b = bq >> 2, q = bq & 3;
    float v = out[(size_t)((b * CCH + o) * QQ + q) * NN + n];
    s += v; s2 += v * v;
  }
  rs[tid] = s; rs2[tid] = s2;
  __syncthreads();
  for (int st = 128; st > 0; st >>= 1) {
    if (tid < st) { rs[tid] += rs[tid + st]; rs2[tid] += rs2[tid + st]; }
    __syncthreads();
  }
  if (tid == 0) {
    float mean = rs[0] / (float)(BQN * NN);
    float var = rs2[0] / (float)(BQN * NN) - mean * mean;
    stats[o] = mean;
    stats[CCH + o] = var;
  }
}

// ---------------- batch-norm apply ----------------
__global__ void bn_kernel(float* __restrict__ out, const float* __restrict__ stats,
                          const float* __restrict__ gq, const float* __restrict__ beta) {
  size_t idx = (size_t)blockIdx.x * 256 + threadIdx.x;
  if (idx >= (size_t)BB * CCH * QQ * NN) return;
  int o = (int)((idx / (QQ * NN)) % CCH);
  float mean = stats[o], var = stats[CCH + o];
  out[idx] = (out[idx] - mean) * rsqrtf(var + EPSF) * gq[o] + beta[o];
}

extern "C" void kernel_launch(void* const* d_in, const int* in_sizes, int n_in,
                              void* d_out, int out_size, void* d_ws, size_t ws_size,
                              hipStream_t stream) {
  const float* x     = (const float*)d_in[0];
  const float* Wq    = (const float*)d_in[1];
  const float* bq    = (const float*)d_in[2];
  const float* Wk    = (const float*)d_in[3];
  const float* bk    = (const float*)d_in[4];
  const float* Wv    = (const float*)d_in[5];
  const float* bv    = (const float*)d_in[6];
  const float* Wp    = (const float*)d_in[7];
  const float* bp    = (const float*)d_in[8];
  const float* gamma = (const float*)d_in[9];
  const float* beta  = (const float*)d_in[10];
  float* out = (float*)d_out;

  // workspace carve (ushort region first, then fp32 region)
  ushort* h   = (ushort*)d_ws;
  ushort* wqh = h;                       // 65536 each
  ushort* wkh = wqh + 65536;
  ushort* wvh = wkh + 65536;
  ushort* wph = wvh + 65536;
  ushort* xT  = wph + 65536;             // [SP][256]   13107200
  ushort* Yq  = xT + (size_t)SP * CCH;   // [256][SP]
  ushort* Yk  = Yq + (size_t)SP * CCH;
  ushort* Vt  = Yk + (size_t)SP * CCH;   // [SP][256]
  ushort* Ot  = Vt + (size_t)SP * CCH;   // [SP][256]
  ushort* P   = Ot + (size_t)SP * CCH;   // [BQN][256][256] bf16
  float*  S   = (float*)(P + (size_t)BQN * CCH * CCH);   // [BQN][256][256] fp32
  float*  gq  = S + (size_t)BQN * CCH * CCH;
  float*  st  = gq + 256;

  quant_weights_kernel<<<1025, 256, 0, stream>>>(Wq, Wk, Wv, Wp, gamma,
                                                 wqh, wkh, wvh, wph, gq);
  transpose_x_kernel<<<dim3(NN / 64, CCH / 64, BQN), 256, 0, stream>>>(x, xT);

  // Q = Wq * xT^T -> Yq[o][s]
  gemm_bt<0><<<dim3(SP / 64, CCH / 64, 1), 256, 0, stream>>>(
      wqh, 256, 0, xT, 256, 0, Yq, SP, 0, bq, 1.f, 256);
  // K = Wk * xT^T -> Yk[o][s]
  gemm_bt<0><<<dim3(SP / 64, CCH / 64, 1), 256, 0, stream>>>(
      wkh, 256, 0, xT, 256, 0, Yk, SP, 0, bk, 1.f, 256);
  // V = Wv * xT^T -> Vt[s][o]  (transposed epilogue)
  gemm_bt<1><<<dim3(SP / 64, CCH / 64, 1), 256, 0, stream>>>(
      wvh, 256, 0, xT, 256, 0, Vt, 256, 0, bv, 1.f, 256);
  // S[bqi][c][d] = 0.125 * Q[c][:] . K[d][:]   (K-contraction over n, fp32 out)
  gemm_bt<2><<<dim3(CCH / 64, CCH / 64, BQN), 256, 0, stream>>>(
      Yq, SP, 1600, Yk, SP, 1600, S, CCH, 65536, nullptr, 0.125f, 1600);
  softmax_kernel<<<BQN * CCH, 256, 0, stream>>>(S, P);
  // O = P * V  -> Ot[s][c] (transposed epilogue)
  gemm_bt<3><<<dim3(NN / 64, CCH / 64, BQN), 256, 0, stream>>>(
      P, 256, 65536, Vt, 256, (long)NN * CCH, Ot, 256, (long)NN * CCH,
      nullptr, 1.f, 256);
  // out = Wp * Ot^T -> out[b][o][q][n] fp32 + bias
  gemm_bt<4><<<dim3(SP / 64, CCH / 64, 1), 256, 0, stream>>>(
      wph, 256, 0, Ot, 256, 0, out, 0, 0, bp, 1.f, 256);

  stats_kernel<<<CCH, 256, 0, stream>>>(out, st);
  bn_kernel<<<(BB * CCH * QQ * NN + 255) / 256, 256, 0, stream>>>(out, st, gq, beta);
}

// Round 3
// 329.546 us; speedup vs baseline: 3.0796x; 1.1263x over previous
//
#include <hip/hip_runtime.h>
#include <math.h>

#define BB 8
#define CCH 256
#define QQ 4
#define NN 1600          // H*W
#define BQN 32           // B*Q
#define SP 51200         // BQN*NN
#define EPSF 1e-5f

typedef __attribute__((ext_vector_type(8))) short bf16x8;  // 8 bf16 (4 VGPRs)
typedef __attribute__((ext_vector_type(4))) float f32x4;

static __device__ inline ushort f2bf(float f) {
  union { float f; unsigned u; } v; v.f = f;
  return (ushort)((v.u + 0x7fffu + ((v.u >> 16) & 1u)) >> 16);  // RNE
}

// async 16B global->LDS (m97 ladder step: width=16). LDS dest must be linear
// in lane order: lane l of wave w lands at base + (w*64+l)*16 bytes.
static __device__ inline void gld16(const ushort* g, ushort* l) {
  __builtin_amdgcn_global_load_lds(
      (const __attribute__((address_space(1))) unsigned int*)g,
      (__attribute__((address_space(3))) unsigned int*)l, 16, 0, 0);
}

// ---------------- fake-quant weights (-> bf16) + gamma (-> fp32) ----------------
__global__ void quant_weights_kernel(const float* Wq, const float* Wk,
                                     const float* Wv, const float* Wp,
                                     const float* gamma,
                                     ushort* wq, ushort* wk, ushort* wv, ushort* wp,
                                     float* gq) {
  __shared__ float red[256];
  int blk = blockIdx.x;
  int tid = threadIdx.x;
  if (blk < 1024) {
    int mat = blk >> 8;
    int row = blk & 255;
    const float* W = (mat == 0) ? Wq : (mat == 1) ? Wk : (mat == 2) ? Wv : Wp;
    ushort* O      = (mat == 0) ? wq : (mat == 1) ? wk : (mat == 2) ? wv : wp;
    float w = W[row * 256 + tid];
    red[tid] = fabsf(w);
    __syncthreads();
    for (int s = 128; s > 0; s >>= 1) {
      if (tid < s) red[tid] = fmaxf(red[tid], red[tid + s]);
      __syncthreads();
    }
    float s = red[0] / 127.0f + 1e-8f;
    float q = fminf(fmaxf(rintf(w / s), -127.0f), 127.0f) * s;
    O[row * 256 + tid] = f2bf(q);
  } else {
    float g = gamma[tid];
    red[tid] = fabsf(g);
    __syncthreads();
    for (int s = 128; s > 0; s >>= 1) {
      if (tid < s) red[tid] = fmaxf(red[tid], red[tid + s]);
      __syncthreads();
    }
    float s = red[0] / 127.0f + 1e-8f;
    float q = fminf(fmaxf(rintf(g / s), -127.0f), 127.0f) * s;
    gq[tid] = q;
  }
}

// ---------------- transpose x: [b][c][q][n] fp32 -> xT[s=bqi*NN+n][c] bf16 ----------------
__global__ __launch_bounds__(256)
void transpose_x_kernel(const float* __restrict__ x, ushort* __restrict__ xT) {
  int bqi = blockIdx.z, b = bqi >> 2, q = bqi & 3;
  int s0 = blockIdx.x * 64, c0 = blockIdx.y * 64;
  __shared__ ushort lT[64 * 66];
  int tid = threadIdx.x;
  int c = tid >> 2, nch = (tid & 3) * 16;
  const float* xp = x + ((size_t)(b * CCH + c0 + c) * QQ + q) * NN + s0 + nch;
#pragma unroll
  for (int j = 0; j < 4; j++) {
    float4 f = ((const float4*)xp)[j];
    lT[c * 66 + nch + j * 4 + 0] = f2bf(f.x);
    lT[c * 66 + nch + j * 4 + 1] = f2bf(f.y);
    lT[c * 66 + nch + j * 4 + 2] = f2bf(f.z);
    lT[c * 66 + nch + j * 4 + 3] = f2bf(f.w);
  }
  __syncthreads();
  int n = tid >> 2, cch = (tid & 3) * 16;
  union { ushort u[16]; int4 v[2]; } o;
#pragma unroll
  for (int i = 0; i < 16; i++) o.u[i] = lT[(cch + i) * 66 + n];
  ushort* dst = xT + (size_t)(bqi * NN + s0 + n) * CCH + c0 + cch;
  *(int4*)dst = o.v[0];
  *((int4*)dst + 1) = o.v[1];
}

// ---------------- 128x128 bf16 MFMA GEMM: C[M][N] = A[M][K] * B[N][K]^T ----------------
// m97 structure: BK=32, global_load_lds width=16, 4 waves in 2x2, each wave
// 64x64 via 4x4 mfma_f32_16x16x32_bf16 accumulators. Unpadded LDS [row][32k]
// (lane-linear, forced by global_load_lds). Per-wave 16x68 fp32 LDS staging
// in the epilogue for vectorized, layout-flexible stores.
// EPI 0: bf16 [m][n]+bias[m]   1: bf16 [n][m]+bias[m]   2: f32 [m][n]*scale
//     3: bf16 [n][m]           4: f32 strided [b][o][q][n]+bias[m]
template<int EPI>
__global__ __launch_bounds__(256)
void gemm128(const ushort* __restrict__ A, int lda, long sA,
             const ushort* __restrict__ B, int ldb, long sB,
             void* __restrict__ Cv, int ldc, long sC,
             const float* __restrict__ bias, float scale, int K, int Nlim)
{
  __shared__ ushort lA[128 * 32];
  __shared__ ushort lB[128 * 32];
  __shared__ float lC[4 * 16 * 68];
  int z = blockIdx.z;
  int mBase = blockIdx.y * 128, nBase = blockIdx.x * 128;
  int tid = threadIdx.x, wave = tid >> 6, lane = tid & 63;
  int wm = wave >> 1, wn = wave & 1;
  int col = lane & 15, quad = lane >> 4;
  int srow = tid >> 2, skc = (tid & 3) * 8;

  const ushort* Az = A + (size_t)z * sA;
  const ushort* Bz = B + (size_t)z * sB;
  const ushort* gA  = Az + (size_t)(mBase + srow) * lda + skc;
  const ushort* gA2 = gA + (size_t)64 * lda;
  int br1 = nBase + srow;      br1 = br1 < Nlim ? br1 : Nlim - 1;
  int br2 = nBase + 64 + srow; br2 = br2 < Nlim ? br2 : Nlim - 1;
  const ushort* gB  = Bz + (size_t)br1 * ldb + skc;
  const ushort* gB2 = Bz + (size_t)br2 * ldb + skc;
  ushort* lA1 = &lA[srow * 32 + skc];
  ushort* lA2 = &lA[(64 + srow) * 32 + skc];
  ushort* lB1 = &lB[srow * 32 + skc];
  ushort* lB2 = &lB[(64 + srow) * 32 + skc];

  f32x4 acc[4][4];
#pragma unroll
  for (int i = 0; i < 4; i++)
#pragma unroll
    for (int j = 0; j < 4; j++) acc[i][j] = (f32x4){0.f, 0.f, 0.f, 0.f};

  for (int kt = 0; kt < K; kt += 32) {
    __syncthreads();
    gld16(gA + kt, lA1);
    gld16(gA2 + kt, lA2);
    gld16(gB + kt, lB1);
    gld16(gB2 + kt, lB2);
    __syncthreads();
    bf16x8 af[4], bfr[4];
#pragma unroll
    for (int i = 0; i < 4; i++)
      af[i] = *(const bf16x8*)&lA[(wm * 64 + i * 16 + col) * 32 + quad * 8];
#pragma unroll
    for (int j = 0; j < 4; j++)
      bfr[j] = *(const bf16x8*)&lB[(wn * 64 + j * 16 + col) * 32 + quad * 8];
#pragma unroll
    for (int i = 0; i < 4; i++)
#pragma unroll
      for (int j = 0; j < 4; j++)
        acc[i][j] = __builtin_amdgcn_mfma_f32_16x16x32_bf16(af[i], bfr[j], acc[i][j], 0, 0, 0);
  }

  // epilogue: per-wave private LDS staging, no cross-wave barrier needed
  float* lCw = &lC[wave * 16 * 68];
  int mW = mBase + wm * 64;
  int nW = nBase + wn * 64;
#pragma unroll
  for (int i = 0; i < 4; i++) {
#pragma unroll
    for (int j = 0; j < 4; j++)
#pragma unroll
      for (int r = 0; r < 4; r++)
        lCw[(quad * 4 + r) * 68 + j * 16 + col] = acc[i][j][r];

    int mrow0 = mW + i * 16;
    if (EPI == 0) {
      int rr = lane & 15, cc = lane >> 4;
      float bi = bias[mrow0 + rr];
      union { ushort u[16]; int4 v[2]; } o;
#pragma unroll
      for (int t = 0; t < 16; t++) o.u[t] = f2bf(lCw[rr * 68 + cc * 16 + t] + bi);
      ushort* C = (ushort*)Cv + (size_t)z * sC + (size_t)(mrow0 + rr) * ldc + nW + cc * 16;
      *(int4*)C = o.v[0];
      *((int4*)C + 1) = o.v[1];
    } else if (EPI == 1 || EPI == 3) {
      int n = nW + lane;
      if (n < Nlim) {
        union { ushort u[16]; int4 v[2]; } o;
#pragma unroll
        for (int t = 0; t < 16; t++) {
          float v = lCw[t * 68 + lane];
          if (EPI == 1) v += bias[mrow0 + t];
          o.u[t] = f2bf(v);
        }
        ushort* C = (ushort*)Cv + (size_t)z * sC + (size_t)n * ldc + mrow0;
        *(int4*)C = o.v[0];
        *((int4*)C + 1) = o.v[1];
      }
    } else if (EPI == 2) {
      int rr = lane & 15, cc = lane >> 4;
      float* C = (float*)Cv + (size_t)z * sC + (size_t)(mrow0 + rr) * ldc + nW + cc * 16;
#pragma unroll
      for (int v = 0; v < 4; v++) {
        float4 f;
        f.x = lCw[rr * 68 + cc * 16 + v * 4 + 0] * scale;
        f.y = lCw[rr * 68 + cc * 16 + v * 4 + 1] * scale;
        f.z = lCw[rr * 68 + cc * 16 + v * 4 + 2] * scale;
        f.w = lCw[rr * 68 + cc * 16 + v * 4 + 3] * scale;
        *(float4*)(C + v * 4) = f;
      }
    } else {  // EPI 4
      int rr = lane & 15, cc = lane >> 4;
      int s0g = nW + cc * 16;
      int bqi = s0g / 1600, n0 = s0g - bqi * 1600;
      int b = bqi >> 2, q = bqi & 3;
      float bi = bias[mrow0 + rr];
      float* C = (float*)Cv + (size_t)b * (CCH * QQ * NN)
               + (size_t)(mrow0 + rr) * (QQ * NN) + (size_t)q * NN + n0;
#pragma unroll
      for (int v = 0; v < 4; v++) {
        float4 f;
        f.x = lCw[rr * 68 + cc * 16 + v * 4 + 0] + bi;
        f.y = lCw[rr * 68 + cc * 16 + v * 4 + 1] + bi;
        f.z = lCw[rr * 68 + cc * 16 + v * 4 + 2] + bi;
        f.w = lCw[rr * 68 + cc * 16 + v * 4 + 3] + bi;
        *(float4*)(C + v * 4) = f;
      }
    }
  }
}

// ---------------- softmax over rows of 256: fp32 S -> bf16 P ----------------
__global__ void softmax_kernel(const float* __restrict__ S, ushort* __restrict__ P) {
  size_t row = blockIdx.x;
  const float* r = S + row * CCH;
  int tid = threadIdx.x;
  __shared__ float red[256];
  float v = r[tid];
  red[tid] = v;
  __syncthreads();
  for (int s = 128; s > 0; s >>= 1) {
    if (tid < s) red[tid] = fmaxf(red[tid], red[tid + s]);
    __syncthreads();
  }
  float m = red[0];
  __syncthreads();
  float e = expf(v - m);
  red[tid] = e;
  __syncthreads();
  for (int s = 128; s > 0; s >>= 1) {
    if (tid < s) red[tid] += red[tid + s];
    __syncthreads();
  }
  P[row * CCH + tid] = f2bf(e / red[0]);
}

// ---------------- stats stage 1: per (channel, batch) contiguous partial sums ----------------
// out[(b*CCH+o)*QQ*NN ...] is contiguous over (q,n) = 6400 floats. grid (CCH, BB).
__global__ __launch_bounds__(256)
void stats1_kernel(const float* __restrict__ out, float* __restrict__ partial) {
  int o = blockIdx.x, p = blockIdx.y;
  const float4* src = (const float4*)(out + ((size_t)p * CCH + o) * (QQ * NN));
  float s = 0.f, s2 = 0.f;
  for (int i = threadIdx.x; i < QQ * NN / 4; i += 256) {
    float4 f = src[i];
    s  += f.x + f.y + f.z + f.w;
    s2 += f.x * f.x + f.y * f.y + f.z * f.z + f.w * f.w;
  }
  __shared__ float rs[256], rs2[256];
  int tid = threadIdx.x;
  rs[tid] = s; rs2[tid] = s2;
  __syncthreads();
  for (int st = 128; st > 0; st >>= 1) {
    if (tid < st) { rs[tid] += rs[tid + st]; rs2[tid] += rs2[tid + st]; }
    __syncthreads();
  }
  if (tid == 0) {
    partial[o * BB + p] = rs[0];
    partial[CCH * BB + o * BB + p] = rs2[0];
  }
}

// ---------------- stats stage 2: finalize mean/var ----------------
__global__ void stats2_kernel(const float* __restrict__ partial, float* __restrict__ st) {
  int o = threadIdx.x;
  float s = 0.f, s2 = 0.f;
#pragma unroll
  for (int p = 0; p < BB; p++) {
    s  += partial[o * BB + p];
    s2 += partial[CCH * BB + o * BB + p];
  }
  float inv = 1.0f / (float)(BQN * NN);
  float mean = s * inv;
  float var = s2 * inv - mean * mean;
  st[o] = mean;
  st[CCH + o] = var;
}

// ---------------- batch-norm apply (float4) ----------------
__global__ __launch_bounds__(256)
void bn_kernel(float* __restrict__ out, const float* __restrict__ st,
               const float* __restrict__ gq, const float* __restrict__ beta) {
  size_t i4 = (size_t)blockIdx.x * 256 + threadIdx.x;  // 3276800 float4s exactly
  int o = (int)((i4 / 1600) & 255);
  float mean = st[o];
  float g = rsqrtf(st[CCH + o] + EPSF) * gq[o];
  float be = beta[o];
  float4 f = ((const float4*)out)[i4];
  f.x = (f.x - mean) * g + be;
  f.y = (f.y - mean) * g + be;
  f.z = (f.z - mean) * g + be;
  f.w = (f.w - mean) * g + be;
  ((float4*)out)[i4] = f;
}

extern "C" void kernel_launch(void* const* d_in, const int* in_sizes, int n_in,
                              void* d_out, int out_size, void* d_ws, size_t ws_size,
                              hipStream_t stream) {
  const float* x     = (const float*)d_in[0];
  const float* Wq    = (const float*)d_in[1];
  const float* bq    = (const float*)d_in[2];
  const float* Wk    = (const float*)d_in[3];
  const float* bk    = (const float*)d_in[4];
  const float* Wv    = (const float*)d_in[5];
  const float* bv    = (const float*)d_in[6];
  const float* Wp    = (const float*)d_in[7];
  const float* bp    = (const float*)d_in[8];
  const float* gamma = (const float*)d_in[9];
  const float* beta  = (const float*)d_in[10];
  float* out = (float*)d_out;

  ushort* h   = (ushort*)d_ws;
  ushort* wqh = h;                       // 65536 each
  ushort* wkh = wqh + 65536;
  ushort* wvh = wkh + 65536;
  ushort* wph = wvh + 65536;
  ushort* xT  = wph + 65536;             // [SP][256]
  ushort* Yq  = xT + (size_t)SP * CCH;   // [256][SP]
  ushort* Yk  = Yq + (size_t)SP * CCH;
  ushort* Vt  = Yk + (size_t)SP * CCH;   // [SP][256]
  ushort* Ot  = Vt + (size_t)SP * CCH;   // [SP][256]
  ushort* P   = Ot + (size_t)SP * CCH;   // [BQN][256][256] bf16
  float*  S   = (float*)(P + (size_t)BQN * CCH * CCH);   // [BQN][256][256] fp32
  float*  gq  = S + (size_t)BQN * CCH * CCH;
  float*  st  = gq + 256;                // 512
  float*  pa  = st + 512;                // 4096 partials

  quant_weights_kernel<<<1025, 256, 0, stream>>>(Wq, Wk, Wv, Wp, gamma,
                                                 wqh, wkh, wvh, wph, gq);
  transpose_x_kernel<<<dim3(NN / 64, CCH / 64, BQN), 256, 0, stream>>>(x, xT);

  // Q = Wq * xT^T -> Yq[o][s]
  gemm128<0><<<dim3(SP / 128, CCH / 128, 1), 256, 0, stream>>>(
      wqh, 256, 0, xT, 256, 0, Yq, SP, 0, bq, 1.f, 256, SP);
  // K
  gemm128<0><<<dim3(SP / 128, CCH / 128, 1), 256, 0, stream>>>(
      wkh, 256, 0, xT, 256, 0, Yk, SP, 0, bk, 1.f, 256, SP);
  // V -> Vt[s][o] (transposed epilogue)
  gemm128<1><<<dim3(SP / 128, CCH / 128, 1), 256, 0, stream>>>(
      wvh, 256, 0, xT, 256, 0, Vt, 256, 0, bv, 1.f, 256, SP);
  // S[bqi][c][d] = 0.125 * Q[c][:].K[d][:]  (K=1600 contraction)
  gemm128<2><<<dim3(CCH / 128, CCH / 128, BQN), 256, 0, stream>>>(
      Yq, SP, 1600, Yk, SP, 1600, S, CCH, 65536, nullptr, 0.125f, 1600, CCH);
  softmax_kernel<<<BQN * CCH, 256, 0, stream>>>(S, P);
  // O = P * V -> Ot[s][c]  (N=1600 per z: 13 tiles, last partial via Nlim)
  gemm128<3><<<dim3((NN + 127) / 128, CCH / 128, BQN), 256, 0, stream>>>(
      P, 256, 65536, Vt, 256, (long)NN * CCH, Ot, 256, (long)NN * CCH,
      nullptr, 1.f, 256, NN);
  // out = Wp * Ot^T -> out[b][o][q][n] fp32 + bias
  gemm128<4><<<dim3(SP / 128, CCH / 128, 1), 256, 0, stream>>>(
      wph, 256, 0, Ot, 256, 0, out, 0, 0, bp, 1.f, 256, SP);

  stats1_kernel<<<dim3(CCH, BB), 256, 0, stream>>>(out, pa);
  stats2_kernel<<<1, 256, 0, stream>>>(pa, st);
  bn_kernel<<<(BB * CCH * QQ * NN / 4) / 256, 256, 0, stream>>>(out, st, gq, beta);
}

// Round 4
// 320.624 us; speedup vs baseline: 3.1653x; 1.0278x over previous
//
#include <hip/hip_runtime.h>
#include <math.h>

#define BB 8
#define CCH 256
#define QQ 4
#define NN 1600          // H*W
#define BQN 32           // B*Q
#define SP 51200         // BQN*NN
#define EPSF 1e-5f

typedef __attribute__((ext_vector_type(8))) short bf16x8;  // 8 bf16 (4 VGPRs)
typedef __attribute__((ext_vector_type(4))) float f32x4;

static __device__ inline ushort f2bf(float f) {
  union { float f; unsigned u; } v; v.f = f;
  return (ushort)((v.u + 0x7fffu + ((v.u >> 16) & 1u)) >> 16);  // RNE
}

// async 16B global->LDS. LDS dest linear in lane order (wave-uniform base + lane*16).
static __device__ inline void gld16(const ushort* g, ushort* l) {
  __builtin_amdgcn_global_load_lds(
      (const __attribute__((address_space(1))) unsigned int*)g,
      (__attribute__((address_space(3))) unsigned int*)l, 16, 0, 0);
}

// ---------------- fake-quant weights (-> bf16, QKV fused) + gamma + bias fuse ----------------
__global__ void quant_weights_kernel(const float* Wq, const float* Wk,
                                     const float* Wv, const float* Wp,
                                     const float* gamma,
                                     const float* bq, const float* bk, const float* bv,
                                     ushort* wqkv, ushort* wp,
                                     float* gq, float* bqkv) {
  __shared__ float red[256];
  int blk = blockIdx.x;
  int tid = threadIdx.x;
  if (blk < 1024) {
    int mat = blk >> 8;
    int row = blk & 255;
    const float* W = (mat == 0) ? Wq : (mat == 1) ? Wk : (mat == 2) ? Wv : Wp;
    ushort* O      = (mat < 3) ? (wqkv + mat * 65536) : wp;
    float w = W[row * 256 + tid];
    red[tid] = fabsf(w);
    __syncthreads();
    for (int s = 128; s > 0; s >>= 1) {
      if (tid < s) red[tid] = fmaxf(red[tid], red[tid + s]);
      __syncthreads();
    }
    float s = red[0] / 127.0f + 1e-8f;
    float q = fminf(fmaxf(rintf(w / s), -127.0f), 127.0f) * s;
    O[row * 256 + tid] = f2bf(q);
  } else {
    float g = gamma[tid];
    red[tid] = fabsf(g);
    __syncthreads();
    for (int s = 128; s > 0; s >>= 1) {
      if (tid < s) red[tid] = fmaxf(red[tid], red[tid + s]);
      __syncthreads();
    }
    float s = red[0] / 127.0f + 1e-8f;
    float q = fminf(fmaxf(rintf(g / s), -127.0f), 127.0f) * s;
    gq[tid] = q;
    bqkv[tid] = bq[tid];
    bqkv[256 + tid] = bk[tid];
    bqkv[512 + tid] = bv[tid];
  }
}

// ---------------- transpose x: [b][c][q][n] fp32 -> xT[s=bqi*NN+n][c] bf16 ----------------
__global__ __launch_bounds__(256)
void transpose_x_kernel(const float* __restrict__ x, ushort* __restrict__ xT) {
  int bqi = blockIdx.z, b = bqi >> 2, q = bqi & 3;
  int s0 = blockIdx.x * 64, c0 = blockIdx.y * 64;
  __shared__ ushort lT[64 * 66];
  int tid = threadIdx.x;
  int c = tid >> 2, nch = (tid & 3) * 16;
  const float* xp = x + ((size_t)(b * CCH + c0 + c) * QQ + q) * NN + s0 + nch;
#pragma unroll
  for (int j = 0; j < 4; j++) {
    float4 f = ((const float4*)xp)[j];
    lT[c * 66 + nch + j * 4 + 0] = f2bf(f.x);
    lT[c * 66 + nch + j * 4 + 1] = f2bf(f.y);
    lT[c * 66 + nch + j * 4 + 2] = f2bf(f.z);
    lT[c * 66 + nch + j * 4 + 3] = f2bf(f.w);
  }
  __syncthreads();
  int n = tid >> 2, cch = (tid & 3) * 16;
  union { ushort u[16]; int4 v[2]; } o;
#pragma unroll
  for (int i = 0; i < 16; i++) o.u[i] = lT[(cch + i) * 66 + n];
  ushort* dst = xT + (size_t)(bqi * NN + s0 + n) * CCH + c0 + cch;
  *(int4*)dst = o.v[0];
  *((int4*)dst + 1) = o.v[1];
}

// ---------------- 128x128 bf16 MFMA GEMM: C[M][N] = A[M][K] * B[N][K]^T ----------------
// EPI 2: f32 [m][n]*scale      3: bf16 [n][m]
//     4: f32 strided [b][o][q][n]+bias[m], + per-row stats partials
//     5: fused QKV: mat0/1 row-major bf16 + bias; mat2 transposed bf16 + bias
// SWAP: blockIdx.x enumerates m-tiles (L2 reuse of B across consecutive blocks)
// SPLITK: z = chunk*32+bqi; chunk covers k in [chunk*416, +min(416,...)) of 1600
template<int EPI, int SWAP, int SPLITK>
__global__ __launch_bounds__(256)
void gemm128(const ushort* __restrict__ A, int lda, long sA,
             const ushort* __restrict__ B, int ldb, long sB,
             void* __restrict__ Cv, int ldc, long sC,
             const float* __restrict__ bias, float scale, int K, int Nlim,
             float* __restrict__ part)
{
  __shared__ ushort lA[128 * 32];
  __shared__ ushort lB[128 * 32];
  __shared__ float lC[4 * 16 * 68];
  __shared__ float psS[128][2], psS2[128][2];
  int z = blockIdx.z;
  int mBase, nBase;
  if (SWAP) { mBase = blockIdx.x * 128; nBase = blockIdx.y * 128; }
  else      { mBase = blockIdx.y * 128; nBase = blockIdx.x * 128; }
  int tid = threadIdx.x, wave = tid >> 6, lane = tid & 63;
  int wm = wave >> 1, wn = wave & 1;
  int col = lane & 15, quad = lane >> 4;
  int srow = tid >> 2, skc = (tid & 3) * 8;

  const ushort* Az;
  const ushort* Bz;
  int Kc = K;
  if (SPLITK) {
    int bqi = z & 31, chunk = z >> 5;
    int kbase = chunk * 416;
    Kc = 1600 - kbase; if (Kc > 416) Kc = 416;
    Az = A + (size_t)bqi * sA + kbase;
    Bz = B + (size_t)bqi * sB + kbase;
  } else {
    Az = A + (size_t)z * sA;
    Bz = B + (size_t)z * sB;
  }
  const ushort* gA  = Az + (size_t)(mBase + srow) * lda + skc;
  const ushort* gA2 = gA + (size_t)64 * lda;
  int br1 = nBase + srow;      br1 = br1 < Nlim ? br1 : Nlim - 1;
  int br2 = nBase + 64 + srow; br2 = br2 < Nlim ? br2 : Nlim - 1;
  const ushort* gB  = Bz + (size_t)br1 * ldb + skc;
  const ushort* gB2 = Bz + (size_t)br2 * ldb + skc;
  ushort* lA1 = &lA[srow * 32 + skc];
  ushort* lA2 = &lA[(64 + srow) * 32 + skc];
  ushort* lB1 = &lB[srow * 32 + skc];
  ushort* lB2 = &lB[(64 + srow) * 32 + skc];

  f32x4 acc[4][4];
#pragma unroll
  for (int i = 0; i < 4; i++)
#pragma unroll
    for (int j = 0; j < 4; j++) acc[i][j] = (f32x4){0.f, 0.f, 0.f, 0.f};

  for (int kt = 0; kt < Kc; kt += 32) {
    __syncthreads();
    gld16(gA + kt, lA1);
    gld16(gA2 + kt, lA2);
    gld16(gB + kt, lB1);
    gld16(gB2 + kt, lB2);
    __syncthreads();
    bf16x8 af[4], bfr[4];
#pragma unroll
    for (int i = 0; i < 4; i++)
      af[i] = *(const bf16x8*)&lA[(wm * 64 + i * 16 + col) * 32 + quad * 8];
#pragma unroll
    for (int j = 0; j < 4; j++)
      bfr[j] = *(const bf16x8*)&lB[(wn * 64 + j * 16 + col) * 32 + quad * 8];
#pragma unroll
    for (int i = 0; i < 4; i++)
#pragma unroll
      for (int j = 0; j < 4; j++)
        acc[i][j] = __builtin_amdgcn_mfma_f32_16x16x32_bf16(af[i], bfr[j], acc[i][j], 0, 0, 0);
  }

  // epilogue: per-wave private LDS staging
  float* lCw = &lC[wave * 16 * 68];
  int mW = mBase + wm * 64;
  int nW = nBase + wn * 64;
#pragma unroll
  for (int i = 0; i < 4; i++) {
#pragma unroll
    for (int j = 0; j < 4; j++)
#pragma unroll
      for (int r = 0; r < 4; r++)
        lCw[(quad * 4 + r) * 68 + j * 16 + col] = acc[i][j][r];

    int mrow0 = mW + i * 16;
    if (EPI == 2) {
      int rr = lane & 15, cc = lane >> 4;
      float* C = (float*)Cv + (size_t)z * sC + (size_t)(mrow0 + rr) * ldc + nW + cc * 16;
#pragma unroll
      for (int v = 0; v < 4; v++) {
        float4 f;
        f.x = lCw[rr * 68 + cc * 16 + v * 4 + 0] * scale;
        f.y = lCw[rr * 68 + cc * 16 + v * 4 + 1] * scale;
        f.z = lCw[rr * 68 + cc * 16 + v * 4 + 2] * scale;
        f.w = lCw[rr * 68 + cc * 16 + v * 4 + 3] * scale;
        *(float4*)(C + v * 4) = f;
      }
    } else if (EPI == 3) {
      int n = nW + lane;
      if (n < Nlim) {
        union { ushort u[16]; int4 v[2]; } o;
#pragma unroll
        for (int t = 0; t < 16; t++) o.u[t] = f2bf(lCw[t * 68 + lane]);
        ushort* C = (ushort*)Cv + (size_t)z * sC + (size_t)n * ldc + mrow0;
        *(int4*)C = o.v[0];
        *((int4*)C + 1) = o.v[1];
      }
    } else if (EPI == 4) {
      int rr = lane & 15, cc = lane >> 4;
      int s0g = nW + cc * 16;
      int bqi = s0g / 1600, n0 = s0g - bqi * 1600;
      int b = bqi >> 2, q = bqi & 3;
      float bi = bias[mrow0 + rr];
      float* C = (float*)Cv + (size_t)b * (CCH * QQ * NN)
               + (size_t)(mrow0 + rr) * (QQ * NN) + (size_t)q * NN + n0;
      float ls = 0.f, ls2 = 0.f;
#pragma unroll
      for (int v = 0; v < 4; v++) {
        float4 f;
        f.x = lCw[rr * 68 + cc * 16 + v * 4 + 0] + bi;
        f.y = lCw[rr * 68 + cc * 16 + v * 4 + 1] + bi;
        f.z = lCw[rr * 68 + cc * 16 + v * 4 + 2] + bi;
        f.w = lCw[rr * 68 + cc * 16 + v * 4 + 3] + bi;
        *(float4*)(C + v * 4) = f;
        ls  += f.x + f.y + f.z + f.w;
        ls2 += f.x * f.x + f.y * f.y + f.z * f.z + f.w * f.w;
      }
      ls  += __shfl_down(ls, 32);  ls  += __shfl_down(ls, 16);
      ls2 += __shfl_down(ls2, 32); ls2 += __shfl_down(ls2, 16);
      if (lane < 16) {
        psS[wm * 64 + i * 16 + lane][wn] = ls;
        psS2[wm * 64 + i * 16 + lane][wn] = ls2;
      }
    } else {  // EPI 5: fused QKV
      int mat = mrow0 >> 8;   // block-uniform (tile never crosses a 256 boundary)
      if (mat < 2) {
        int rr = lane & 15, cc = lane >> 4;
        int g = mrow0 + rr;
        float bi = bias[g];
        union { ushort u[16]; int4 v[2]; } o;
#pragma unroll
        for (int t = 0; t < 16; t++) o.u[t] = f2bf(lCw[rr * 68 + cc * 16 + t] + bi);
        ushort* C = (ushort*)Cv + (size_t)mat * 256 * ldc
                  + (size_t)(g & 255) * ldc + nW + cc * 16;
        *(int4*)C = o.v[0];
        *((int4*)C + 1) = o.v[1];
      } else {
        int n = nW + lane;
        union { ushort u[16]; int4 v[2]; } o;
#pragma unroll
        for (int t = 0; t < 16; t++)
          o.u[t] = f2bf(lCw[t * 68 + lane] + bias[mrow0 + t]);
        ushort* C = (ushort*)Cv + (size_t)2 * 256 * ldc + (size_t)n * 256 + (mrow0 & 255);
        *(int4*)C = o.v[0];
        *((int4*)C + 1) = o.v[1];
      }
    }
  }
  if (EPI == 4) {
    __syncthreads();
    if (tid < 128) {
      float s  = psS[tid][0] + psS[tid][1];
      float s2 = psS2[tid][0] + psS2[tid][1];
      int xt = blockIdx.x;
      part[(size_t)xt * 256 + mBase + tid] = s;
      part[400 * 256 + (size_t)xt * 256 + mBase + tid] = s2;
    }
  }
}

// ---------------- softmax: sum 4 split-K partials, *0.125, softmax, -> bf16 P ----------------
__global__ void softmax_kernel(const float* __restrict__ Sp, ushort* __restrict__ P) {
  int bi = blockIdx.x;               // 0..8191
  int bqi = bi >> 8, r = bi & 255;
  int tid = threadIdx.x;
  size_t off = (size_t)bqi * 65536 + (size_t)r * 256 + tid;
  const size_t cs = (size_t)32 * 65536;
  float v = 0.125f * (Sp[off] + Sp[off + cs] + Sp[off + 2 * cs] + Sp[off + 3 * cs]);
  __shared__ float red[256];
  red[tid] = v;
  __syncthreads();
  for (int s = 128; s > 0; s >>= 1) {
    if (tid < s) red[tid] = fmaxf(red[tid], red[tid + s]);
    __syncthreads();
  }
  float m = red[0];
  __syncthreads();
  float e = expf(v - m);
  red[tid] = e;
  __syncthreads();
  for (int s = 128; s > 0; s >>= 1) {
    if (tid < s) red[tid] += red[tid + s];
    __syncthreads();
  }
  P[off] = f2bf(e / red[0]);
}

// ---------------- stats finalize: reduce 400 partials per channel ----------------
__global__ void stats2_kernel(const float* __restrict__ part, float* __restrict__ st) {
  int o = blockIdx.x;
  int tid = threadIdx.x;
  float s = 0.f, s2 = 0.f;
  for (int x = tid; x < 400; x += 256) {
    s  += part[(size_t)x * 256 + o];
    s2 += part[400 * 256 + (size_t)x * 256 + o];
  }
  __shared__ float rs[256], rs2[256];
  rs[tid] = s; rs2[tid] = s2;
  __syncthreads();
  for (int t = 128; t > 0; t >>= 1) {
    if (tid < t) { rs[tid] += rs[tid + t]; rs2[tid] += rs2[tid + t]; }
    __syncthreads();
  }
  if (tid == 0) {
    float inv = 1.0f / (float)(BQN * NN);
    float mean = rs[0] * inv;
    float var = rs2[0] * inv - mean * mean;
    st[o] = mean;
    st[CCH + o] = var;
  }
}

// ---------------- batch-norm apply (float4) ----------------
__global__ __launch_bounds__(256)
void bn_kernel(float* __restrict__ out, const float* __restrict__ st,
               const float* __restrict__ gq, const float* __restrict__ beta) {
  size_t i4 = (size_t)blockIdx.x * 256 + threadIdx.x;  // 3276800 float4s exactly
  int o = (int)((i4 / 1600) & 255);
  float mean = st[o];
  float g = rsqrtf(st[CCH + o] + EPSF) * gq[o];
  float be = beta[o];
  float4 f = ((const float4*)out)[i4];
  f.x = (f.x - mean) * g + be;
  f.y = (f.y - mean) * g + be;
  f.z = (f.z - mean) * g + be;
  f.w = (f.w - mean) * g + be;
  ((float4*)out)[i4] = f;
}

extern "C" void kernel_launch(void* const* d_in, const int* in_sizes, int n_in,
                              void* d_out, int out_size, void* d_ws, size_t ws_size,
                              hipStream_t stream) {
  const float* x     = (const float*)d_in[0];
  const float* Wq    = (const float*)d_in[1];
  const float* bq    = (const float*)d_in[2];
  const float* Wk    = (const float*)d_in[3];
  const float* bk    = (const float*)d_in[4];
  const float* Wv    = (const float*)d_in[5];
  const float* bv    = (const float*)d_in[6];
  const float* Wp    = (const float*)d_in[7];
  const float* bp    = (const float*)d_in[8];
  const float* gamma = (const float*)d_in[9];
  const float* beta  = (const float*)d_in[10];
  float* out = (float*)d_out;

  // ws layout (Sp overlays dead xT to keep footprint ~144 MB)
  ushort* h    = (ushort*)d_ws;
  ushort* wqkv = h;                          // 768*256 = 196608
  ushort* wph  = wqkv + 196608;              // 65536
  ushort* qkv  = wph + 65536;                // Yq|Yk|Vt : 3 * 256*SP
  ushort* Yq   = qkv;
  ushort* Yk   = qkv + (size_t)256 * SP;
  ushort* Vt   = qkv + (size_t)2 * 256 * SP;
  ushort* Ot   = qkv + (size_t)3 * 256 * SP; // [SP][256]
  ushort* P    = Ot + (size_t)SP * CCH;      // [BQN][256][256] bf16
  ushort* xT   = P + (size_t)BQN * CCH * CCH; // [SP][256] bf16 (dead after QKV gemm)
  float*  Sp   = (float*)xT;                 // [4][BQN][256][256] fp32 overlays xT+
  float*  gq   = Sp + (size_t)4 * BQN * CCH * CCH;
  float*  st   = gq + 256;                   // 512
  float*  part = st + 512;                   // 2*400*256

  quant_weights_kernel<<<1025, 256, 0, stream>>>(Wq, Wk, Wv, Wp, gamma, bq, bk, bv,
                                                 wqkv, wph, gq, part /*unused*/);
  // note: bqkv stored in gq+? -- use dedicated buffer: reuse 'part' head is unsafe
  // (part written later). Use st+512.. actually allocate after part:
  float* bqkv = part + 2 * 400 * 256;
  quant_weights_kernel<<<1025, 256, 0, stream>>>(Wq, Wk, Wv, Wp, gamma, bq, bk, bv,
                                                 wqkv, wph, gq, bqkv);
  transpose_x_kernel<<<dim3(NN / 64, CCH / 64, BQN), 256, 0, stream>>>(x, xT);

  // fused QKV: [768]x[SP] = wqkv * xT^T ; Q,K row-major, V transposed
  gemm128<5, 1, 0><<<dim3(6, 400, 1), 256, 0, stream>>>(
      wqkv, 256, 0, xT, 256, 0, qkv, SP, 0, bqkv, 1.f, 256, SP, nullptr);
  // scores split-K=4: Sp[chunk*32+bqi][c][d] = Q[c][:].K[d][:] over k-chunk
  gemm128<2, 0, 1><<<dim3(2, 2, 128), 256, 0, stream>>>(
      Yq, SP, 1600, Yk, SP, 1600, Sp, CCH, 65536, nullptr, 1.f, 416, CCH, nullptr);
  softmax_kernel<<<BQN * CCH, 256, 0, stream>>>(Sp, P);
  // O = P * V -> Ot[s][c]
  gemm128<3, 0, 0><<<dim3((NN + 127) / 128, 2, BQN), 256, 0, stream>>>(
      P, 256, 65536, Vt, 256, (long)NN * CCH, Ot, 256, (long)NN * CCH,
      nullptr, 1.f, 256, NN, nullptr);
  // out = Wp * Ot^T -> out[b][o][q][n] fp32 + bias, + stats partials
  gemm128<4, 0, 0><<<dim3(SP / 128, 2, 1), 256, 0, stream>>>(
      wph, 256, 0, Ot, 256, 0, out, 0, 0, bp, 1.f, 256, SP, part);

  stats2_kernel<<<CCH, 256, 0, stream>>>(part, st);
  bn_kernel<<<(BB * CCH * QQ * NN / 4) / 256, 256, 0, stream>>>(out, st, gq, beta);
}

// Round 5
// 312.789 us; speedup vs baseline: 3.2446x; 1.0250x over previous
//
#include <hip/hip_runtime.h>
#include <math.h>

#define BB 8
#define CCH 256
#define QQ 4
#define NN 1600          // H*W
#define BQN 32           // B*Q
#define SP 51200         // BQN*NN
#define EPSF 1e-5f

typedef __attribute__((ext_vector_type(8))) short bf16x8;  // 8 bf16 (4 VGPRs)
typedef __attribute__((ext_vector_type(4))) float f32x4;

static __device__ inline ushort f2bf(float f) {
  union { float f; unsigned u; } v; v.f = f;
  return (ushort)((v.u + 0x7fffu + ((v.u >> 16) & 1u)) >> 16);  // RNE
}

// async 16B global->LDS. LDS dest linear in lane order (wave-uniform base + lane*16).
static __device__ inline void gld16(const ushort* g, ushort* l) {
  __builtin_amdgcn_global_load_lds(
      (const __attribute__((address_space(1))) unsigned int*)g,
      (__attribute__((address_space(3))) unsigned int*)l, 16, 0, 0);
}

// ---------------- fake-quant weights (-> bf16, QKV fused) + gamma + bias fuse ----------------
__global__ void quant_weights_kernel(const float* Wq, const float* Wk,
                                     const float* Wv, const float* Wp,
                                     const float* gamma,
                                     const float* bq, const float* bk, const float* bv,
                                     ushort* wqkv, ushort* wp,
                                     float* gq, float* bqkv) {
  __shared__ float red[256];
  int blk = blockIdx.x;
  int tid = threadIdx.x;
  if (blk < 1024) {
    int mat = blk >> 8;
    int row = blk & 255;
    const float* W = (mat == 0) ? Wq : (mat == 1) ? Wk : (mat == 2) ? Wv : Wp;
    ushort* O      = (mat < 3) ? (wqkv + mat * 65536) : wp;
    float w = W[row * 256 + tid];
    red[tid] = fabsf(w);
    __syncthreads();
    for (int s = 128; s > 0; s >>= 1) {
      if (tid < s) red[tid] = fmaxf(red[tid], red[tid + s]);
      __syncthreads();
    }
    float s = red[0] / 127.0f + 1e-8f;
    float q = fminf(fmaxf(rintf(w / s), -127.0f), 127.0f) * s;
    O[row * 256 + tid] = f2bf(q);
  } else {
    float g = gamma[tid];
    red[tid] = fabsf(g);
    __syncthreads();
    for (int s = 128; s > 0; s >>= 1) {
      if (tid < s) red[tid] = fmaxf(red[tid], red[tid + s]);
      __syncthreads();
    }
    float s = red[0] / 127.0f + 1e-8f;
    float q = fminf(fmaxf(rintf(g / s), -127.0f), 127.0f) * s;
    gq[tid] = q;
    bqkv[tid] = bq[tid];
    bqkv[256 + tid] = bk[tid];
    bqkv[512 + tid] = bv[tid];
  }
}

// ---------------- transpose x: [b][c][q][n] fp32 -> xT[s=bqi*NN+n][c] bf16 ----------------
__global__ __launch_bounds__(256)
void transpose_x_kernel(const float* __restrict__ x, ushort* __restrict__ xT) {
  int bqi = blockIdx.z, b = bqi >> 2, q = bqi & 3;
  int s0 = blockIdx.x * 64, c0 = blockIdx.y * 64;
  __shared__ ushort lT[64 * 66];
  int tid = threadIdx.x;
  int c = tid >> 2, nch = (tid & 3) * 16;
  const float* xp = x + ((size_t)(b * CCH + c0 + c) * QQ + q) * NN + s0 + nch;
#pragma unroll
  for (int j = 0; j < 4; j++) {
    float4 f = ((const float4*)xp)[j];
    lT[c * 66 + nch + j * 4 + 0] = f2bf(f.x);
    lT[c * 66 + nch + j * 4 + 1] = f2bf(f.y);
    lT[c * 66 + nch + j * 4 + 2] = f2bf(f.z);
    lT[c * 66 + nch + j * 4 + 3] = f2bf(f.w);
  }
  __syncthreads();
  int n = tid >> 2, cch = (tid & 3) * 16;
  union { ushort u[16]; int4 v[2]; } o;
#pragma unroll
  for (int i = 0; i < 16; i++) o.u[i] = lT[(cch + i) * 66 + n];
  ushort* dst = xT + (size_t)(bqi * NN + s0 + n) * CCH + c0 + cch;
  *(int4*)dst = o.v[0];
  *((int4*)dst + 1) = o.v[1];
}

// ---------------- 128x128 bf16 MFMA GEMM: C[M][N] = A[M][K] * B[N][K]^T ----------------
// EPI 2: f32 [m][n]*scale      3: bf16 [n][m]
//     4: f32 strided [b][o][q][n]+bias[m], + per-row stats partials
//     5: fused QKV: mat0/1 row-major bf16 + bias; mat2 transposed bf16 + bias
// SWAP: blockIdx.x enumerates m-tiles
// SPLITK: z = chunk*32+bqi; chunk covers k in [chunk*416, +min(416,...)) of 1600
// SWIZ: 1-D grid; xcd=blk&7, l=blk>>3: m-tile=l%6, n-tile=(l/6)*8+xcd
//       (all 6 m-tiles of an n-tile on one XCD -> B-tile L2 reuse)
// LDS: lA/lB (16.4 KB) overlaid with epilogue lC (17.4 KB) + psS (2 KB);
//      one barrier after the K-loop guards the reuse. Total 19.5 KB.
template<int EPI, int SWAP, int SPLITK, int SWIZ>
__global__ __launch_bounds__(256)
void gemm128(const ushort* __restrict__ A, int lda, long sA,
             const ushort* __restrict__ B, int ldb, long sB,
             void* __restrict__ Cv, int ldc, long sC,
             const float* __restrict__ bias, float scale, int K, int Nlim,
             float* __restrict__ part)
{
  __shared__ __align__(16) char smem[19456];
  ushort* lA = (ushort*)smem;                    // 128*32 ushort = 8192 B
  ushort* lB = (ushort*)(smem + 8192);           // 8192 B
  float*  lC = (float*)smem;                     // 4*16*68*4 = 17408 B (post-loop)
  float*  psS  = (float*)(smem + 17408);         // [128][2] = 1024 B
  float*  psS2 = (float*)(smem + 17408 + 1024);  // 1024 B

  int z = blockIdx.z;
  int mBase, nBase;
  if (SWIZ) {
    int blk = blockIdx.x;
    int xcd = blk & 7, l = blk >> 3;
    mBase = (l % 6) * 128;
    nBase = ((l / 6) * 8 + xcd) * 128;
  } else if (SWAP) { mBase = blockIdx.x * 128; nBase = blockIdx.y * 128; }
  else             { mBase = blockIdx.y * 128; nBase = blockIdx.x * 128; }
  int tid = threadIdx.x, wave = tid >> 6, lane = tid & 63;
  int wm = wave >> 1, wn = wave & 1;
  int col = lane & 15, quad = lane >> 4;
  int srow = tid >> 2, skc = (tid & 3) * 8;

  const ushort* Az;
  const ushort* Bz;
  int Kc = K;
  if (SPLITK) {
    int bqi = z & 31, chunk = z >> 5;
    int kbase = chunk * 416;
    Kc = 1600 - kbase; if (Kc > 416) Kc = 416;
    Az = A + (size_t)bqi * sA + kbase;
    Bz = B + (size_t)bqi * sB + kbase;
  } else {
    Az = A + (size_t)z * sA;
    Bz = B + (size_t)z * sB;
  }
  const ushort* gA  = Az + (size_t)(mBase + srow) * lda + skc;
  const ushort* gA2 = gA + (size_t)64 * lda;
  int br1 = nBase + srow;      br1 = br1 < Nlim ? br1 : Nlim - 1;
  int br2 = nBase + 64 + srow; br2 = br2 < Nlim ? br2 : Nlim - 1;
  const ushort* gB  = Bz + (size_t)br1 * ldb + skc;
  const ushort* gB2 = Bz + (size_t)br2 * ldb + skc;
  ushort* lA1 = &lA[srow * 32 + skc];
  ushort* lA2 = &lA[(64 + srow) * 32 + skc];
  ushort* lB1 = &lB[srow * 32 + skc];
  ushort* lB2 = &lB[(64 + srow) * 32 + skc];

  f32x4 acc[4][4];
#pragma unroll
  for (int i = 0; i < 4; i++)
#pragma unroll
    for (int j = 0; j < 4; j++) acc[i][j] = (f32x4){0.f, 0.f, 0.f, 0.f};

  for (int kt = 0; kt < Kc; kt += 32) {
    __syncthreads();
    gld16(gA + kt, lA1);
    gld16(gA2 + kt, lA2);
    gld16(gB + kt, lB1);
    gld16(gB2 + kt, lB2);
    __syncthreads();
    bf16x8 af[4], bfr[4];
#pragma unroll
    for (int i = 0; i < 4; i++)
      af[i] = *(const bf16x8*)&lA[(wm * 64 + i * 16 + col) * 32 + quad * 8];
#pragma unroll
    for (int j = 0; j < 4; j++)
      bfr[j] = *(const bf16x8*)&lB[(wn * 64 + j * 16 + col) * 32 + quad * 8];
#pragma unroll
    for (int i = 0; i < 4; i++)
#pragma unroll
      for (int j = 0; j < 4; j++)
        acc[i][j] = __builtin_amdgcn_mfma_f32_16x16x32_bf16(af[i], bfr[j], acc[i][j], 0, 0, 0);
  }

  __syncthreads();  // all waves done reading lA/lB -> safe to reuse as lC

  // epilogue: per-wave private LDS staging
  float* lCw = lC + wave * 16 * 68;
  int mW = mBase + wm * 64;
  int nW = nBase + wn * 64;
#pragma unroll
  for (int i = 0; i < 4; i++) {
#pragma unroll
    for (int j = 0; j < 4; j++)
#pragma unroll
      for (int r = 0; r < 4; r++)
        lCw[(quad * 4 + r) * 68 + j * 16 + col] = acc[i][j][r];

    int mrow0 = mW + i * 16;
    if (EPI == 2) {
      int rr = lane & 15, cc = lane >> 4;
      float* C = (float*)Cv + (size_t)z * sC + (size_t)(mrow0 + rr) * ldc + nW + cc * 16;
#pragma unroll
      for (int v = 0; v < 4; v++) {
        float4 f;
        f.x = lCw[rr * 68 + cc * 16 + v * 4 + 0] * scale;
        f.y = lCw[rr * 68 + cc * 16 + v * 4 + 1] * scale;
        f.z = lCw[rr * 68 + cc * 16 + v * 4 + 2] * scale;
        f.w = lCw[rr * 68 + cc * 16 + v * 4 + 3] * scale;
        *(float4*)(C + v * 4) = f;
      }
    } else if (EPI == 3) {
      int n = nW + lane;
      if (n < Nlim) {
        union { ushort u[16]; int4 v[2]; } o;
#pragma unroll
        for (int t = 0; t < 16; t++) o.u[t] = f2bf(lCw[t * 68 + lane]);
        ushort* C = (ushort*)Cv + (size_t)z * sC + (size_t)n * ldc + mrow0;
        *(int4*)C = o.v[0];
        *((int4*)C + 1) = o.v[1];
      }
    } else if (EPI == 4) {
      int rr = lane & 15, cc = lane >> 4;
      int s0g = nW + cc * 16;
      int bqi = s0g / 1600, n0 = s0g - bqi * 1600;
      int b = bqi >> 2, q = bqi & 3;
      float bi = bias[mrow0 + rr];
      float* C = (float*)Cv + (size_t)b * (CCH * QQ * NN)
               + (size_t)(mrow0 + rr) * (QQ * NN) + (size_t)q * NN + n0;
      float ls = 0.f, ls2 = 0.f;
#pragma unroll
      for (int v = 0; v < 4; v++) {
        float4 f;
        f.x = lCw[rr * 68 + cc * 16 + v * 4 + 0] + bi;
        f.y = lCw[rr * 68 + cc * 16 + v * 4 + 1] + bi;
        f.z = lCw[rr * 68 + cc * 16 + v * 4 + 2] + bi;
        f.w = lCw[rr * 68 + cc * 16 + v * 4 + 3] + bi;
        *(float4*)(C + v * 4) = f;
        ls  += f.x + f.y + f.z + f.w;
        ls2 += f.x * f.x + f.y * f.y + f.z * f.z + f.w * f.w;
      }
      ls  += __shfl_down(ls, 32);  ls  += __shfl_down(ls, 16);
      ls2 += __shfl_down(ls2, 32); ls2 += __shfl_down(ls2, 16);
      if (lane < 16) {
        psS[(wm * 64 + i * 16 + lane) * 2 + wn] = ls;
        psS2[(wm * 64 + i * 16 + lane) * 2 + wn] = ls2;
      }
    } else {  // EPI 5: fused QKV
      int mat = mrow0 >> 8;   // block-uniform (tile never crosses a 256 boundary)
      if (mat < 2) {
        int rr = lane & 15, cc = lane >> 4;
        int g = mrow0 + rr;
        float bi = bias[g];
        union { ushort u[16]; int4 v[2]; } o;
#pragma unroll
        for (int t = 0; t < 16; t++) o.u[t] = f2bf(lCw[rr * 68 + cc * 16 + t] + bi);
        ushort* C = (ushort*)Cv + (size_t)mat * 256 * ldc
                  + (size_t)(g & 255) * ldc + nW + cc * 16;
        *(int4*)C = o.v[0];
        *((int4*)C + 1) = o.v[1];
      } else {
        int n = nW + lane;
        union { ushort u[16]; int4 v[2]; } o;
#pragma unroll
        for (int t = 0; t < 16; t++)
          o.u[t] = f2bf(lCw[t * 68 + lane] + bias[mrow0 + t]);
        ushort* C = (ushort*)Cv + (size_t)2 * 256 * ldc + (size_t)n * 256 + (mrow0 & 255);
        *(int4*)C = o.v[0];
        *((int4*)C + 1) = o.v[1];
      }
    }
  }
  if (EPI == 4) {
    __syncthreads();
    if (tid < 128) {
      float s  = psS[tid * 2 + 0] + psS[tid * 2 + 1];
      float s2 = psS2[tid * 2 + 0] + psS2[tid * 2 + 1];
      int xt = blockIdx.x;
      part[(size_t)xt * 256 + mBase + tid] = s;
      part[400 * 256 + (size_t)xt * 256 + mBase + tid] = s2;
    }
  }
}

// ---------------- softmax: sum 4 split-K partials, *0.125, softmax, -> bf16 P ----------------
__global__ void softmax_kernel(const float* __restrict__ Sp, ushort* __restrict__ P) {
  int bi = blockIdx.x;               // 0..8191
  int bqi = bi >> 8, r = bi & 255;
  int tid = threadIdx.x;
  size_t off = (size_t)bqi * 65536 + (size_t)r * 256 + tid;
  const size_t cs = (size_t)32 * 65536;
  float v = 0.125f * (Sp[off] + Sp[off + cs] + Sp[off + 2 * cs] + Sp[off + 3 * cs]);
  __shared__ float red[256];
  red[tid] = v;
  __syncthreads();
  for (int s = 128; s > 0; s >>= 1) {
    if (tid < s) red[tid] = fmaxf(red[tid], red[tid + s]);
    __syncthreads();
  }
  float m = red[0];
  __syncthreads();
  float e = expf(v - m);
  red[tid] = e;
  __syncthreads();
  for (int s = 128; s > 0; s >>= 1) {
    if (tid < s) red[tid] += red[tid + s];
    __syncthreads();
  }
  P[off] = f2bf(e / red[0]);
}

// ---------------- stats finalize: reduce 400 partials per channel ----------------
__global__ void stats2_kernel(const float* __restrict__ part, float* __restrict__ st) {
  int o = blockIdx.x;
  int tid = threadIdx.x;
  float s = 0.f, s2 = 0.f;
  for (int x = tid; x < 400; x += 256) {
    s  += part[(size_t)x * 256 + o];
    s2 += part[400 * 256 + (size_t)x * 256 + o];
  }
  __shared__ float rs[256], rs2[256];
  rs[tid] = s; rs2[tid] = s2;
  __syncthreads();
  for (int t = 128; t > 0; t >>= 1) {
    if (tid < t) { rs[tid] += rs[tid + t]; rs2[tid] += rs2[tid + t]; }
    __syncthreads();
  }
  if (tid == 0) {
    float inv = 1.0f / (float)(BQN * NN);
    float mean = rs[0] * inv;
    float var = rs2[0] * inv - mean * mean;
    st[o] = mean;
    st[CCH + o] = var;
  }
}

// ---------------- batch-norm apply (float4) ----------------
__global__ __launch_bounds__(256)
void bn_kernel(float* __restrict__ out, const float* __restrict__ st,
               const float* __restrict__ gq, const float* __restrict__ beta) {
  size_t i4 = (size_t)blockIdx.x * 256 + threadIdx.x;  // 3276800 float4s exactly
  int o = (int)((i4 / 1600) & 255);
  float mean = st[o];
  float g = rsqrtf(st[CCH + o] + EPSF) * gq[o];
  float be = beta[o];
  float4 f = ((const float4*)out)[i4];
  f.x = (f.x - mean) * g + be;
  f.y = (f.y - mean) * g + be;
  f.z = (f.z - mean) * g + be;
  f.w = (f.w - mean) * g + be;
  ((float4*)out)[i4] = f;
}

extern "C" void kernel_launch(void* const* d_in, const int* in_sizes, int n_in,
                              void* d_out, int out_size, void* d_ws, size_t ws_size,
                              hipStream_t stream) {
  const float* x     = (const float*)d_in[0];
  const float* Wq    = (const float*)d_in[1];
  const float* bq    = (const float*)d_in[2];
  const float* Wk    = (const float*)d_in[3];
  const float* bk    = (const float*)d_in[4];
  const float* Wv    = (const float*)d_in[5];
  const float* bv    = (const float*)d_in[6];
  const float* Wp    = (const float*)d_in[7];
  const float* bp    = (const float*)d_in[8];
  const float* gamma = (const float*)d_in[9];
  const float* beta  = (const float*)d_in[10];
  float* out = (float*)d_out;

  // ws layout (Sp overlays dead xT)
  ushort* h    = (ushort*)d_ws;
  ushort* wqkv = h;                          // 768*256 = 196608
  ushort* wph  = wqkv + 196608;              // 65536
  ushort* qkv  = wph + 65536;                // Yq|Yk|Vt : 3 * 256*SP
  ushort* Yq   = qkv;
  ushort* Yk   = qkv + (size_t)256 * SP;
  ushort* Vt   = qkv + (size_t)2 * 256 * SP;
  ushort* Ot   = qkv + (size_t)3 * 256 * SP; // [SP][256]
  ushort* P    = Ot + (size_t)SP * CCH;      // [BQN][256][256] bf16
  ushort* xT   = P + (size_t)BQN * CCH * CCH; // [SP][256] bf16 (dead after QKV gemm)
  float*  Sp   = (float*)xT;                 // [4][BQN][256][256] fp32 overlays xT+
  float*  gq   = Sp + (size_t)4 * BQN * CCH * CCH;
  float*  st   = gq + 256;                   // 512
  float*  part = st + 512;                   // 2*400*256
  float*  bqkv = part + 2 * 400 * 256;       // 768

  quant_weights_kernel<<<1025, 256, 0, stream>>>(Wq, Wk, Wv, Wp, gamma, bq, bk, bv,
                                                 wqkv, wph, gq, bqkv);
  transpose_x_kernel<<<dim3(NN / 64, CCH / 64, BQN), 256, 0, stream>>>(x, xT);

  // fused QKV: [768]x[SP] = wqkv * xT^T ; Q,K row-major, V transposed.
  // XCD-swizzled 1-D grid: 6 m-tiles of each n-tile on one XCD (L2 reuse).
  gemm128<5, 0, 0, 1><<<2400, 256, 0, stream>>>(
      wqkv, 256, 0, xT, 256, 0, qkv, SP, 0, bqkv, 1.f, 256, SP, nullptr);
  // scores split-K=4: Sp[chunk*32+bqi][c][d] = Q[c][:].K[d][:] over k-chunk
  gemm128<2, 0, 1, 0><<<dim3(2, 2, 128), 256, 0, stream>>>(
      Yq, SP, 1600, Yk, SP, 1600, Sp, CCH, 65536, nullptr, 1.f, 416, CCH, nullptr);
  softmax_kernel<<<BQN * CCH, 256, 0, stream>>>(Sp, P);
  // O = P * V -> Ot[s][c]
  gemm128<3, 0, 0, 0><<<dim3((NN + 127) / 128, 2, BQN), 256, 0, stream>>>(
      P, 256, 65536, Vt, 256, (long)NN * CCH, Ot, 256, (long)NN * CCH,
      nullptr, 1.f, 256, NN, nullptr);
  // out = Wp * Ot^T -> out[b][o][q][n] fp32 + bias, + stats partials
  gemm128<4, 0, 0, 0><<<dim3(SP / 128, 2, 1), 256, 0, stream>>>(
      wph, 256, 0, Ot, 256, 0, out, 0, 0, bp, 1.f, 256, SP, part);

  stats2_kernel<<<CCH, 256, 0, stream>>>(part, st);
  bn_kernel<<<(BB * CCH * QQ * NN / 4) / 256, 256, 0, stream>>>(out, st, gq, beta);
}

// Round 6
// 303.205 us; speedup vs baseline: 3.3472x; 1.0316x over previous
//
#include <hip/hip_runtime.h>
#include <math.h>

#define BB 8
#define CCH 256
#define QQ 4
#define NN 1600          // H*W
#define BQN 32           // B*Q
#define SP 51200         // BQN*NN
#define EPSF 1e-5f

typedef __attribute__((ext_vector_type(8))) short bf16x8;  // 8 bf16 (4 VGPRs)
typedef __attribute__((ext_vector_type(4))) float f32x4;

static __device__ inline ushort f2bf(float f) {
  union { float f; unsigned u; } v; v.f = f;
  return (ushort)((v.u + 0x7fffu + ((v.u >> 16) & 1u)) >> 16);  // RNE
}

// async 16B global->LDS. LDS dest linear in lane order (wave-uniform base + lane*16).
static __device__ inline void gld16(const ushort* g, ushort* l) {
  __builtin_amdgcn_global_load_lds(
      (const __attribute__((address_space(1))) unsigned int*)g,
      (__attribute__((address_space(3))) unsigned int*)l, 16, 0, 0);
}

// ---------------- fake-quant weights (-> bf16, QKV fused) + gamma + bias fuse ----------------
__global__ void quant_weights_kernel(const float* Wq, const float* Wk,
                                     const float* Wv, const float* Wp,
                                     const float* gamma,
                                     const float* bq, const float* bk, const float* bv,
                                     ushort* wqkv, ushort* wp,
                                     float* gq, float* bqkv) {
  __shared__ float red[256];
  int blk = blockIdx.x;
  int tid = threadIdx.x;
  if (blk < 1024) {
    int mat = blk >> 8;
    int row = blk & 255;
    const float* W = (mat == 0) ? Wq : (mat == 1) ? Wk : (mat == 2) ? Wv : Wp;
    ushort* O      = (mat < 3) ? (wqkv + mat * 65536) : wp;
    float w = W[row * 256 + tid];
    red[tid] = fabsf(w);
    __syncthreads();
    for (int s = 128; s > 0; s >>= 1) {
      if (tid < s) red[tid] = fmaxf(red[tid], red[tid + s]);
      __syncthreads();
    }
    float s = red[0] / 127.0f + 1e-8f;
    float q = fminf(fmaxf(rintf(w / s), -127.0f), 127.0f) * s;
    O[row * 256 + tid] = f2bf(q);
  } else {
    float g = gamma[tid];
    red[tid] = fabsf(g);
    __syncthreads();
    for (int s = 128; s > 0; s >>= 1) {
      if (tid < s) red[tid] = fmaxf(red[tid], red[tid + s]);
      __syncthreads();
    }
    float s = red[0] / 127.0f + 1e-8f;
    float q = fminf(fmaxf(rintf(g / s), -127.0f), 127.0f) * s;
    gq[tid] = q;
    bqkv[tid] = bq[tid];
    bqkv[256 + tid] = bk[tid];
    bqkv[512 + tid] = bv[tid];
  }
}

// ---------------- transpose x: [b][c][q][n] fp32 -> xT[s=bqi*NN+n][c] bf16 ----------------
__global__ __launch_bounds__(256)
void transpose_x_kernel(const float* __restrict__ x, ushort* __restrict__ xT) {
  int bqi = blockIdx.z, b = bqi >> 2, q = bqi & 3;
  int s0 = blockIdx.x * 64, c0 = blockIdx.y * 64;
  __shared__ ushort lT[64 * 66];
  int tid = threadIdx.x;
  int c = tid >> 2, nch = (tid & 3) * 16;
  const float* xp = x + ((size_t)(b * CCH + c0 + c) * QQ + q) * NN + s0 + nch;
#pragma unroll
  for (int j = 0; j < 4; j++) {
    float4 f = ((const float4*)xp)[j];
    lT[c * 66 + nch + j * 4 + 0] = f2bf(f.x);
    lT[c * 66 + nch + j * 4 + 1] = f2bf(f.y);
    lT[c * 66 + nch + j * 4 + 2] = f2bf(f.z);
    lT[c * 66 + nch + j * 4 + 3] = f2bf(f.w);
  }
  __syncthreads();
  int n = tid >> 2, cch = (tid & 3) * 16;
  union { ushort u[16]; int4 v[2]; } o;
#pragma unroll
  for (int i = 0; i < 16; i++) o.u[i] = lT[(cch + i) * 66 + n];
  ushort* dst = xT + (size_t)(bqi * NN + s0 + n) * CCH + c0 + cch;
  *(int4*)dst = o.v[0];
  *((int4*)dst + 1) = o.v[1];
}

// ---------------- 128x128 bf16 MFMA GEMM: C[M][N] = A[M][K] * B[N][K]^T ----------------
// Double-buffered K-loop (prefetch-after-barrier): one barrier per iter; the
// vmcnt(0) drain before each barrier waits only for the prefetch issued one
// compute-phase ago. EPI/SWAP/SPLITK/SWIZ as before.
// LDS: 2 x 16 KB staging buffers; epilogue lC (17.4 KB) + psS overlay them.
template<int EPI, int SWAP, int SPLITK, int SWIZ>
__global__ __launch_bounds__(256)
void gemm128(const ushort* __restrict__ A, int lda, long sA,
             const ushort* __restrict__ B, int ldb, long sB,
             void* __restrict__ Cv, int ldc, long sC,
             const float* __restrict__ bias, float scale, int K, int Nlim,
             float* __restrict__ part)
{
  __shared__ __align__(16) char smem[32768];
  // buf b: lA at b*16384, lB at b*16384+8192 (each 128 rows x 32 k ushort)
  float*  lC   = (float*)smem;                   // 17408 B, post-loop overlay
  float*  psS  = (float*)(smem + 17408);         // 1024 B
  float*  psS2 = (float*)(smem + 18432);         // 1024 B

  int z = blockIdx.z;
  int mBase, nBase;
  if (SWIZ) {
    int blk = blockIdx.x;
    int xcd = blk & 7, l = blk >> 3;
    mBase = (l % 6) * 128;
    nBase = ((l / 6) * 8 + xcd) * 128;
  } else if (SWAP) { mBase = blockIdx.x * 128; nBase = blockIdx.y * 128; }
  else             { mBase = blockIdx.y * 128; nBase = blockIdx.x * 128; }
  int tid = threadIdx.x, wave = tid >> 6, lane = tid & 63;
  int wm = wave >> 1, wn = wave & 1;
  int col = lane & 15, quad = lane >> 4;
  int srow = tid >> 2, skc = (tid & 3) * 8;

  const ushort* Az;
  const ushort* Bz;
  int Kc = K;
  if (SPLITK) {
    int bqi = z & 31, chunk = z >> 5;
    int kbase = chunk * 416;
    Kc = 1600 - kbase; if (Kc > 416) Kc = 416;
    Az = A + (size_t)bqi * sA + kbase;
    Bz = B + (size_t)bqi * sB + kbase;
  } else {
    Az = A + (size_t)z * sA;
    Bz = B + (size_t)z * sB;
  }
  const ushort* gA  = Az + (size_t)(mBase + srow) * lda + skc;
  const ushort* gA2 = gA + (size_t)64 * lda;
  int br1 = nBase + srow;      br1 = br1 < Nlim ? br1 : Nlim - 1;
  int br2 = nBase + 64 + srow; br2 = br2 < Nlim ? br2 : Nlim - 1;
  const ushort* gB  = Bz + (size_t)br1 * ldb + skc;
  const ushort* gB2 = Bz + (size_t)br2 * ldb + skc;
  // per-thread staging slots in each buffer (lane-linear: tid*16 bytes)
  ushort* sA1[2]; ushort* sA2[2]; ushort* sB1[2]; ushort* sB2[2];
#pragma unroll
  for (int b = 0; b < 2; b++) {
    ushort* lAb = (ushort*)(smem + b * 16384);
    ushort* lBb = (ushort*)(smem + b * 16384 + 8192);
    sA1[b] = &lAb[srow * 32 + skc];
    sA2[b] = &lAb[(64 + srow) * 32 + skc];
    sB1[b] = &lBb[srow * 32 + skc];
    sB2[b] = &lBb[(64 + srow) * 32 + skc];
  }

  f32x4 acc[4][4];
#pragma unroll
  for (int i = 0; i < 4; i++)
#pragma unroll
    for (int j = 0; j < 4; j++) acc[i][j] = (f32x4){0.f, 0.f, 0.f, 0.f};

  int nIter = Kc >> 5;            // Kc is a multiple of 32 (256/416/352)
  // prologue: prefetch tile 0 into buf 0
  gld16(gA, sA1[0]);
  gld16(gA2, sA2[0]);
  gld16(gB, sB1[0]);
  gld16(gB2, sB2[0]);

  for (int it = 0; it < nIter; ++it) {
    int cur = it & 1;
    __syncthreads();              // drains gld(it): buf[cur] ready; buf[1-cur] free
    if (it + 1 < nIter) {
      int kt = (it + 1) << 5;
      int nxt = cur ^ 1;
      gld16(gA + kt, sA1[nxt]);
      gld16(gA2 + kt, sA2[nxt]);
      gld16(gB + kt, sB1[nxt]);
      gld16(gB2 + kt, sB2[nxt]);
    }
    const ushort* lAc = (const ushort*)(smem + cur * 16384);
    const ushort* lBc = (const ushort*)(smem + cur * 16384 + 8192);
    bf16x8 af[4], bfr[4];
#pragma unroll
    for (int i = 0; i < 4; i++)
      af[i] = *(const bf16x8*)&lAc[(wm * 64 + i * 16 + col) * 32 + quad * 8];
#pragma unroll
    for (int j = 0; j < 4; j++)
      bfr[j] = *(const bf16x8*)&lBc[(wn * 64 + j * 16 + col) * 32 + quad * 8];
#pragma unroll
    for (int i = 0; i < 4; i++)
#pragma unroll
      for (int j = 0; j < 4; j++)
        acc[i][j] = __builtin_amdgcn_mfma_f32_16x16x32_bf16(af[i], bfr[j], acc[i][j], 0, 0, 0);
  }

  __syncthreads();  // all waves done with staging -> safe to overlay lC

  // epilogue: per-wave private LDS staging
  float* lCw = lC + wave * 16 * 68;
  int mW = mBase + wm * 64;
  int nW = nBase + wn * 64;
#pragma unroll
  for (int i = 0; i < 4; i++) {
#pragma unroll
    for (int j = 0; j < 4; j++)
#pragma unroll
      for (int r = 0; r < 4; r++)
        lCw[(quad * 4 + r) * 68 + j * 16 + col] = acc[i][j][r];

    int mrow0 = mW + i * 16;
    if (EPI == 2) {
      int rr = lane & 15, cc = lane >> 4;
      float* C = (float*)Cv + (size_t)z * sC + (size_t)(mrow0 + rr) * ldc + nW + cc * 16;
#pragma unroll
      for (int v = 0; v < 4; v++) {
        float4 f;
        f.x = lCw[rr * 68 + cc * 16 + v * 4 + 0] * scale;
        f.y = lCw[rr * 68 + cc * 16 + v * 4 + 1] * scale;
        f.z = lCw[rr * 68 + cc * 16 + v * 4 + 2] * scale;
        f.w = lCw[rr * 68 + cc * 16 + v * 4 + 3] * scale;
        *(float4*)(C + v * 4) = f;
      }
    } else if (EPI == 3) {
      int n = nW + lane;
      if (n < Nlim) {
        union { ushort u[16]; int4 v[2]; } o;
#pragma unroll
        for (int t = 0; t < 16; t++) o.u[t] = f2bf(lCw[t * 68 + lane]);
        ushort* C = (ushort*)Cv + (size_t)z * sC + (size_t)n * ldc + mrow0;
        *(int4*)C = o.v[0];
        *((int4*)C + 1) = o.v[1];
      }
    } else if (EPI == 4) {
      int rr = lane & 15, cc = lane >> 4;
      int s0g = nW + cc * 16;
      int bqi = s0g / 1600, n0 = s0g - bqi * 1600;
      int b = bqi >> 2, q = bqi & 3;
      float bi = bias[mrow0 + rr];
      float* C = (float*)Cv + (size_t)b * (CCH * QQ * NN)
               + (size_t)(mrow0 + rr) * (QQ * NN) + (size_t)q * NN + n0;
      float ls = 0.f, ls2 = 0.f;
#pragma unroll
      for (int v = 0; v < 4; v++) {
        float4 f;
        f.x = lCw[rr * 68 + cc * 16 + v * 4 + 0] + bi;
        f.y = lCw[rr * 68 + cc * 16 + v * 4 + 1] + bi;
        f.z = lCw[rr * 68 + cc * 16 + v * 4 + 2] + bi;
        f.w = lCw[rr * 68 + cc * 16 + v * 4 + 3] + bi;
        *(float4*)(C + v * 4) = f;
        ls  += f.x + f.y + f.z + f.w;
        ls2 += f.x * f.x + f.y * f.y + f.z * f.z + f.w * f.w;
      }
      ls  += __shfl_down(ls, 32);  ls  += __shfl_down(ls, 16);
      ls2 += __shfl_down(ls2, 32); ls2 += __shfl_down(ls2, 16);
      if (lane < 16) {
        psS[(wm * 64 + i * 16 + lane) * 2 + wn] = ls;
        psS2[(wm * 64 + i * 16 + lane) * 2 + wn] = ls2;
      }
    } else {  // EPI 5: fused QKV
      int mat = mrow0 >> 8;   // block-uniform (tile never crosses a 256 boundary)
      if (mat < 2) {
        int rr = lane & 15, cc = lane >> 4;
        int g = mrow0 + rr;
        float bi = bias[g];
        union { ushort u[16]; int4 v[2]; } o;
#pragma unroll
        for (int t = 0; t < 16; t++) o.u[t] = f2bf(lCw[rr * 68 + cc * 16 + t] + bi);
        ushort* C = (ushort*)Cv + (size_t)mat * 256 * ldc
                  + (size_t)(g & 255) * ldc + nW + cc * 16;
        *(int4*)C = o.v[0];
        *((int4*)C + 1) = o.v[1];
      } else {
        int n = nW + lane;
        union { ushort u[16]; int4 v[2]; } o;
#pragma unroll
        for (int t = 0; t < 16; t++)
          o.u[t] = f2bf(lCw[t * 68 + lane] + bias[mrow0 + t]);
        ushort* C = (ushort*)Cv + (size_t)2 * 256 * ldc + (size_t)n * 256 + (mrow0 & 255);
        *(int4*)C = o.v[0];
        *((int4*)C + 1) = o.v[1];
      }
    }
  }
  if (EPI == 4) {
    __syncthreads();
    if (tid < 128) {
      float s  = psS[tid * 2 + 0] + psS[tid * 2 + 1];
      float s2 = psS2[tid * 2 + 0] + psS2[tid * 2 + 1];
      int xt = blockIdx.x;
      part[(size_t)xt * 256 + mBase + tid] = s;
      part[400 * 256 + (size_t)xt * 256 + mBase + tid] = s2;
    }
  }
}

// ---------------- softmax: sum 4 split-K partials, *0.125, softmax, -> bf16 P ----------------
__global__ void softmax_kernel(const float* __restrict__ Sp, ushort* __restrict__ P) {
  int bi = blockIdx.x;               // 0..8191
  int bqi = bi >> 8, r = bi & 255;
  int tid = threadIdx.x;
  size_t off = (size_t)bqi * 65536 + (size_t)r * 256 + tid;
  const size_t cs = (size_t)32 * 65536;
  float v = 0.125f * (Sp[off] + Sp[off + cs] + Sp[off + 2 * cs] + Sp[off + 3 * cs]);
  __shared__ float red[256];
  red[tid] = v;
  __syncthreads();
  for (int s = 128; s > 0; s >>= 1) {
    if (tid < s) red[tid] = fmaxf(red[tid], red[tid + s]);
    __syncthreads();
  }
  float m = red[0];
  __syncthreads();
  float e = expf(v - m);
  red[tid] = e;
  __syncthreads();
  for (int s = 128; s > 0; s >>= 1) {
    if (tid < s) red[tid] += red[tid + s];
    __syncthreads();
  }
  P[off] = f2bf(e / red[0]);
}

// ---------------- stats finalize: reduce 400 partials per channel ----------------
__global__ void stats2_kernel(const float* __restrict__ part, float* __restrict__ st) {
  int o = blockIdx.x;
  int tid = threadIdx.x;
  float s = 0.f, s2 = 0.f;
  for (int x = tid; x < 400; x += 256) {
    s  += part[(size_t)x * 256 + o];
    s2 += part[400 * 256 + (size_t)x * 256 + o];
  }
  __shared__ float rs[256], rs2[256];
  rs[tid] = s; rs2[tid] = s2;
  __syncthreads();
  for (int t = 128; t > 0; t >>= 1) {
    if (tid < t) { rs[tid] += rs[tid + t]; rs2[tid] += rs2[tid + t]; }
    __syncthreads();
  }
  if (tid == 0) {
    float inv = 1.0f / (float)(BQN * NN);
    float mean = rs[0] * inv;
    float var = rs2[0] * inv - mean * mean;
    st[o] = mean;
    st[CCH + o] = var;
  }
}

// ---------------- batch-norm apply (float4) ----------------
__global__ __launch_bounds__(256)
void bn_kernel(float* __restrict__ out, const float* __restrict__ st,
               const float* __restrict__ gq, const float* __restrict__ beta) {
  size_t i4 = (size_t)blockIdx.x * 256 + threadIdx.x;  // 3276800 float4s exactly
  int o = (int)((i4 / 1600) & 255);
  float mean = st[o];
  float g = rsqrtf(st[CCH + o] + EPSF) * gq[o];
  float be = beta[o];
  float4 f = ((const float4*)out)[i4];
  f.x = (f.x - mean) * g + be;
  f.y = (f.y - mean) * g + be;
  f.z = (f.z - mean) * g + be;
  f.w = (f.w - mean) * g + be;
  ((float4*)out)[i4] = f;
}

extern "C" void kernel_launch(void* const* d_in, const int* in_sizes, int n_in,
                              void* d_out, int out_size, void* d_ws, size_t ws_size,
                              hipStream_t stream) {
  const float* x     = (const float*)d_in[0];
  const float* Wq    = (const float*)d_in[1];
  const float* bq    = (const float*)d_in[2];
  const float* Wk    = (const float*)d_in[3];
  const float* bk    = (const float*)d_in[4];
  const float* Wv    = (const float*)d_in[5];
  const float* bv    = (const float*)d_in[6];
  const float* Wp    = (const float*)d_in[7];
  const float* bp    = (const float*)d_in[8];
  const float* gamma = (const float*)d_in[9];
  const float* beta  = (const float*)d_in[10];
  float* out = (float*)d_out;

  // ws layout (Sp overlays dead xT)
  ushort* h    = (ushort*)d_ws;
  ushort* wqkv = h;                          // 768*256 = 196608
  ushort* wph  = wqkv + 196608;              // 65536
  ushort* qkv  = wph + 65536;                // Yq|Yk|Vt : 3 * 256*SP
  ushort* Yq   = qkv;
  ushort* Yk   = qkv + (size_t)256 * SP;
  ushort* Vt   = qkv + (size_t)2 * 256 * SP;
  ushort* Ot   = qkv + (size_t)3 * 256 * SP; // [SP][256]
  ushort* P    = Ot + (size_t)SP * CCH;      // [BQN][256][256] bf16
  ushort* xT   = P + (size_t)BQN * CCH * CCH; // [SP][256] bf16 (dead after QKV gemm)
  float*  Sp   = (float*)xT;                 // [4][BQN][256][256] fp32 overlays xT+
  float*  gq   = Sp + (size_t)4 * BQN * CCH * CCH;
  float*  st   = gq + 256;                   // 512
  float*  part = st + 512;                   // 2*400*256
  float*  bqkv = part + 2 * 400 * 256;       // 768

  quant_weights_kernel<<<1025, 256, 0, stream>>>(Wq, Wk, Wv, Wp, gamma, bq, bk, bv,
                                                 wqkv, wph, gq, bqkv);
  transpose_x_kernel<<<dim3(NN / 64, CCH / 64, BQN), 256, 0, stream>>>(x, xT);

  // fused QKV: [768]x[SP] = wqkv * xT^T ; Q,K row-major, V transposed.
  // XCD-swizzled 1-D grid: 6 m-tiles of each n-tile on one XCD (L2 reuse).
  gemm128<5, 0, 0, 1><<<2400, 256, 0, stream>>>(
      wqkv, 256, 0, xT, 256, 0, qkv, SP, 0, bqkv, 1.f, 256, SP, nullptr);
  // scores split-K=4: Sp[chunk*32+bqi][c][d] = Q[c][:].K[d][:] over k-chunk
  gemm128<2, 0, 1, 0><<<dim3(2, 2, 128), 256, 0, stream>>>(
      Yq, SP, 1600, Yk, SP, 1600, Sp, CCH, 65536, nullptr, 1.f, 416, CCH, nullptr);
  softmax_kernel<<<BQN * CCH, 256, 0, stream>>>(Sp, P);
  // O = P * V -> Ot[s][c]
  gemm128<3, 0, 0, 0><<<dim3((NN + 127) / 128, 2, BQN), 256, 0, stream>>>(
      P, 256, 65536, Vt, 256, (long)NN * CCH, Ot, 256, (long)NN * CCH,
      nullptr, 1.f, 256, NN, nullptr);
  // out = Wp * Ot^T -> out[b][o][q][n] fp32 + bias, + stats partials
  gemm128<4, 0, 0, 0><<<dim3(SP / 128, 2, 1), 256, 0, stream>>>(
      wph, 256, 0, Ot, 256, 0, out, 0, 0, bp, 1.f, 256, SP, part);

  stats2_kernel<<<CCH, 256, 0, stream>>>(part, st);
  bn_kernel<<<(BB * CCH * QQ * NN / 4) / 256, 256, 0, stream>>>(out, st, gq, beta);
}